// Round 13
// baseline (256.655 us; speedup 1.0000x reference)
//
#include <hip/hip_runtime.h>
#include <hip/hip_bf16.h>

typedef __bf16 bf16x8 __attribute__((ext_vector_type(8)));
typedef __bf16 bf16x4 __attribute__((ext_vector_type(4)));
typedef float f32x4 __attribute__((ext_vector_type(4)));
typedef float f32x2 __attribute__((ext_vector_type(2)));

__device__ __forceinline__ f32x4 mfma16(bf16x8 a, bf16x8 b, f32x4 c) {
  return __builtin_amdgcn_mfma_f32_16x16x32_bf16(a, b, c, 0, 0, 0);
}

__device__ __forceinline__ bf16x8 cvt8(const float* f) {
  bf16x8 r;
#pragma unroll
  for (int i = 0; i < 8; ++i) r[i] = (__bf16)f[i];
  return r;
}

// ---- block reduction helper (blockDim.x == 256, 4 waves) ----
__device__ __forceinline__ void blockRed2(float& a, float& b, float* red) {
#pragma unroll
  for (int off = 1; off < 64; off <<= 1) {
    a += __shfl_xor(a, off, 64);
    b += __shfl_xor(b, off, 64);
  }
  const int w = threadIdx.x >> 6;
  if ((threadIdx.x & 63) == 0) { red[w] = a; red[4 + w] = b; }
  __syncthreads();
  a = red[0] + red[1] + red[2] + red[3];
  b = red[4] + red[5] + red[6] + red[7];
  __syncthreads();
}

// =====================================================================
// Stage A: img_feat partials = images_flat(512x37632) @ W_img(37632x512)
// split-K=49, tile 128x128, BK=64, 12 K-steps (half the barrier drains
// of BK=32 -- drain count, not BW, is the bottleneck), 8 waves, dbuf
// LDS (72KB), DEPTH-1 register staging (32 regs -- the depth-2 BK=64
// variant spilled: WRITE 25->84MB). XCD-chunked swizzle.
// =====================================================================
#define IMG_K 37632
#define SPLITK 49
#define STEPS_PER 12  // 768 k per z-slice / 64

__global__ __launch_bounds__(512) void img_gemm_kernel(
    const float* __restrict__ A, const float* __restrict__ B,
    __bf16* __restrict__ partials) {
  __shared__ __bf16 As[2][128 * 72];
  __shared__ __bf16 Bs[2][128 * 72];
  const int t = threadIdx.x;
  const int lane = t & 63;
  const int w = t >> 6;
  const int wr = (w >> 2) * 64;
  const int wc = (w & 3) * 32;
  // XCD-chunked bijective swizzle: 784 blocks = 8 XCDs x 98.
  const int orig = blockIdx.x + (blockIdx.y << 2) + (blockIdx.z << 4);
  const int swz = (orig & 7) * 98 + (orig >> 3);
  const int m0 = ((swz >> 2) & 3) * 128;
  const int n0 = (swz & 3) * 128;
  const int zz = swz >> 4;
  const int kbase = zz * STEPS_PER * 64;

  f32x4 acc[4][2];
#pragma unroll
  for (int i = 0; i < 4; ++i)
#pragma unroll
    for (int j = 0; j < 2; ++j) acc[i][j] = f32x4{0.f, 0.f, 0.f, 0.f};

  const int ar = t >> 2, ak = (t & 3) * 16;
  const int bn = t & 127, bk = (t >> 7) * 16;
  const int fr = lane & 15, fk = (lane >> 4) * 8;

  float a0[16], b0[16];
#define IMG_LOAD(K0)                                                        \
  do {                                                                      \
    const float* asrc = A + (size_t)(m0 + ar) * IMG_K + (K0) + ak;          \
    _Pragma("unroll") for (int p = 0; p < 4; ++p) {                         \
      f32x4 v = *reinterpret_cast<const f32x4*>(asrc + p * 4);              \
      a0[p * 4 + 0] = v[0]; a0[p * 4 + 1] = v[1];                           \
      a0[p * 4 + 2] = v[2]; a0[p * 4 + 3] = v[3];                           \
    }                                                                       \
    const float* bsrc = B + (size_t)((K0) + bk) * 512 + n0 + bn;            \
    _Pragma("unroll") for (int j = 0; j < 16; ++j) b0[j] =                  \
        bsrc[(size_t)j * 512];                                              \
  } while (0)
#define IMG_WRITE(BUF)                                                      \
  do {                                                                      \
    *reinterpret_cast<bf16x8*>(&As[BUF][ar * 72 + ak]) = cvt8(a0);          \
    *reinterpret_cast<bf16x8*>(&As[BUF][ar * 72 + ak + 8]) = cvt8(a0 + 8);  \
    *reinterpret_cast<bf16x8*>(&Bs[BUF][bn * 72 + bk]) = cvt8(b0);          \
    *reinterpret_cast<bf16x8*>(&Bs[BUF][bn * 72 + bk + 8]) = cvt8(b0 + 8);  \
  } while (0)
#define IMG_MFMA(BUF)                                                       \
  do {                                                                      \
    _Pragma("unroll") for (int ks = 0; ks < 2; ++ks) {                      \
      bf16x8 af[4], bfr[2];                                                 \
      _Pragma("unroll") for (int i = 0; i < 4; ++i) af[i] =                 \
          *reinterpret_cast<const bf16x8*>(                                 \
              &As[BUF][(wr + i * 16 + fr) * 72 + ks * 32 + fk]);            \
      _Pragma("unroll") for (int j = 0; j < 2; ++j) bfr[j] =                \
          *reinterpret_cast<const bf16x8*>(                                 \
              &Bs[BUF][(wc + j * 16 + fr) * 72 + ks * 32 + fk]);            \
      _Pragma("unroll") for (int i = 0; i < 4; ++i)                         \
          _Pragma("unroll") for (int j = 0; j < 2; ++j) acc[i][j] =         \
              mfma16(af[i], bfr[j], acc[i][j]);                             \
    }                                                                       \
  } while (0)

  IMG_LOAD(kbase);
  IMG_WRITE(0);
  __syncthreads();

  for (int s = 0; s < STEPS_PER; ++s) {
    const int cur = s & 1;
    const bool more = (s + 1) < STEPS_PER;
    if (more) IMG_LOAD(kbase + (s + 1) * 64);  // hides under MFMA
    IMG_MFMA(cur);
    if (more) IMG_WRITE(cur ^ 1);
    __syncthreads();
  }
#undef IMG_LOAD
#undef IMG_WRITE
#undef IMG_MFMA

  __bf16* P = partials + (size_t)zz * (512 * 512);
  const int rq = (lane >> 4) * 4;
#pragma unroll
  for (int i = 0; i < 4; ++i)
#pragma unroll
    for (int j = 0; j < 2; ++j)
#pragma unroll
      for (int r = 0; r < 4; ++r)
        P[(size_t)(m0 + wr + i * 16 + rq + r) * 512 + (n0 + wc + j * 16 + fr)] =
            (__bf16)acc[i][j][r];
}

// low[idx] = kp_feat(already there) + b_img + sum_z partials[z][idx];
// also writes bf16 copy into fusedbf[:, 0:512] (row stride 1024).
__global__ __launch_bounds__(256) void reduce_add_kernel(
    const __bf16* __restrict__ partials, const float* __restrict__ b_img,
    float* __restrict__ low, __bf16* __restrict__ fusedbf) {
  const int idx = blockIdx.x * 256 + threadIdx.x;
  float acc = low[idx] + b_img[idx & 511];
#pragma unroll
  for (int z = 0; z < SPLITK; ++z)
    acc += (float)partials[(size_t)z * 262144 + idx];
  low[idx] = acc;
  fusedbf[(size_t)(idx >> 9) * 1024 + (idx & 511)] = (__bf16)acc;
}

// =====================================================================
// Bodies for the fused prep kernel (transposes + kp, all independent)
// =====================================================================
__device__ __forceinline__ void wtrans_body(const float* __restrict__ W,
                                            __bf16* __restrict__ Wt, int NC,
                                            int NK, int bx, int by) {
  __shared__ float T[32][33];
  const int t = threadIdx.x;
  const int c0 = bx * 32;
  const int k0 = by * 32;
#pragma unroll
  for (int r = 0; r < 4; ++r) {
    const int idx = r * 256 + t;
    const int i = idx >> 5, j = idx & 31;
    const int c = c0 + j;
    T[i][j] = (c < NC) ? W[(size_t)(k0 + i) * NC + c] : 0.f;
  }
  __syncthreads();
#pragma unroll
  for (int r = 0; r < 4; ++r) {
    const int idx = r * 256 + t;
    const int i = idx >> 5, j = idx & 31;
    const int c = c0 + i;
    if (c < NC) Wt[(size_t)c * NK + k0 + j] = (__bf16)T[j][i];
  }
}

__device__ __forceinline__ void kp_body(
    const float* __restrict__ kp, const float* __restrict__ W,
    const float* __restrict__ bias, const float* __restrict__ g,
    const float* __restrict__ bt, float* __restrict__ low, int row) {
  __shared__ float rowv[242];
  __shared__ float red[8];
  const int t = threadIdx.x;
  const size_t roff = (size_t)row * 242;
  if (t < 242) rowv[t] = kp[roff + t];
  __syncthreads();
  const int d0 = t, d1 = t + 256;
  float p0 = bias[d0], p1 = bias[d1];
  for (int kk = 0; kk < 242; ++kk) {
    const float x = rowv[kk];
    p0 = fmaf(x, W[kk * 512 + d0], p0);
    p1 = fmaf(x, W[kk * 512 + d1], p1);
  }
  p0 = fmaxf(p0, 0.f);
  p1 = fmaxf(p1, 0.f);
  float s = p0 + p1, sq = p0 * p0 + p1 * p1;
  blockRed2(s, sq, red);
  const float m = s * (1.f / 512.f);
  const float var = sq * (1.f / 512.f) - m * m;
  const float rs = rsqrtf(var + 1e-5f);
  const size_t off = (size_t)row * 512;
  low[off + d0] = (p0 - m) * rs * g[d0] + bt[d0];
  low[off + d1] = (p1 - m) * rs * g[d1] + bt[d1];
}

// One launch for: wqp transpose (512) + Wq/Wk/Wv/Wo transposes (1024)
// + W_ctc transpose (1312) + kp_feat (512). Total 3360 blocks.
__global__ __launch_bounds__(256) void prep_kernel(
    const float* __restrict__ W_qp, __bf16* __restrict__ wtq,
    const float* __restrict__ Wq, const float* __restrict__ Wk,
    const float* __restrict__ Wv, const float* __restrict__ Wo,
    __bf16* __restrict__ wq_t, __bf16* __restrict__ wk_t,
    __bf16* __restrict__ wv_t, __bf16* __restrict__ wo_t,
    const float* __restrict__ W_ctc, __bf16* __restrict__ wtc,
    const float* __restrict__ kp, const float* __restrict__ W_kp,
    const float* __restrict__ b_kp, const float* __restrict__ g_kp,
    const float* __restrict__ bt_kp, float* __restrict__ low) {
  const int bid = blockIdx.x;
  if (bid < 512) {
    const int c = bid, t = threadIdx.x;
    wtq[(size_t)c * 256 + t] =
        (t < 242) ? (__bf16)W_qp[(size_t)t * 512 + c] : (__bf16)0.f;
  } else if (bid < 1536) {
    const int idx = bid - 512;
    const int z = idx >> 8, rem = idx & 255;
    const float* W = (z == 0) ? Wq : (z == 1) ? Wk : (z == 2) ? Wv : Wo;
    __bf16* Wt = (z == 0) ? wq_t : (z == 1) ? wk_t : (z == 2) ? wv_t : wo_t;
    wtrans_body(W, Wt, 512, 512, rem & 15, rem >> 4);
  } else if (bid < 2848) {
    const int idx = bid - 1536;  // 1312 = 41 x 32
    wtrans_body(W_ctc, wtc, 1296, 1024, idx % 41, idx / 41);
  } else {
    kp_body(kp, W_kp, b_kp, g_kp, bt_kp, low, bid - 2848);
  }
}

// =====================================================================
// Fused MFMA pooling: pooled = pool_mean(LN(qgrids @ W_qp + b_qp)) bf16
// =====================================================================
__global__ __launch_bounds__(512) void pool_mfma_kernel(
    const float* __restrict__ qgrids, const int* __restrict__ lens,
    const __bf16* __restrict__ Wt, const float* __restrict__ bias,
    const float* __restrict__ g, const float* __restrict__ bt,
    __bf16* __restrict__ pooled) {
  __shared__ float red[8][16][2];
  const int t = threadIdx.x, lane = t & 63, w = t >> 6;
  const int b = blockIdx.x >> 5;
  const int j0 = (blockIdx.x & 31) * 16;
  const int L = lens[b];
  int S = (L + 511) >> 9;
  if (S < 1) S = 1;
  const int new_len = (L + S - 1) / S;
  const float* qg_b = qgrids + (size_t)b * 4096 * 242;
  __bf16* pooled_b = pooled + (size_t)b * 512 * 512;

  const int fr = lane & 15;
  const int fq = lane >> 4;
  const int fkq = fq * 8;
  const int colbase = w * 64;

  float biasv[4], gv[4], btv[4];
#pragma unroll
  for (int nt = 0; nt < 4; ++nt) {
    const int col = colbase + nt * 16 + fr;
    biasv[nt] = bias[col];
    gv[nt] = g[col];
    btv[nt] = bt[col];
  }

  f32x4 pool[4];
#pragma unroll
  for (int nt = 0; nt < 4; ++nt) pool[nt] = f32x4{0.f, 0.f, 0.f, 0.f};

  for (int i = 0; i < S; ++i) {
    const int arow = (j0 + fr) * S + i;
    const float* asrc = qg_b + (size_t)arow * 242;
    f32x4 acc[4];
#pragma unroll
    for (int nt = 0; nt < 4; ++nt) acc[nt] = f32x4{0.f, 0.f, 0.f, 0.f};
#pragma unroll
    for (int ks = 0; ks < 8; ++ks) {
      bf16x8 af;
      if (ks < 7) {
        float tmp[8];
#pragma unroll
        for (int p2 = 0; p2 < 4; ++p2) {
          f32x2 v = *reinterpret_cast<const f32x2*>(asrc + ks * 32 + fkq + p2 * 2);
          tmp[p2 * 2] = v[0];
          tmp[p2 * 2 + 1] = v[1];
        }
        af = cvt8(tmp);
      } else {
        float tmp[8];
#pragma unroll
        for (int jj = 0; jj < 8; ++jj) {
          const int kk = 224 + fkq + jj;
          tmp[jj] = (kk < 242) ? asrc[kk] : 0.f;
        }
        af = cvt8(tmp);
      }
      const __bf16* wt = Wt + ks * 32 + fkq;
#pragma unroll
      for (int nt = 0; nt < 4; ++nt) {
        bf16x8 bfv = *reinterpret_cast<const bf16x8*>(
            wt + (size_t)(colbase + nt * 16 + fr) * 256);
        acc[nt] = mfma16(af, bfv, acc[nt]);
      }
    }
    float s[4] = {0.f, 0.f, 0.f, 0.f}, sq[4] = {0.f, 0.f, 0.f, 0.f};
#pragma unroll
    for (int nt = 0; nt < 4; ++nt) {
#pragma unroll
      for (int r = 0; r < 4; ++r) {
        const float v = acc[nt][r] + biasv[nt];
        acc[nt][r] = v;
        s[r] += v;
        sq[r] += v * v;
      }
    }
#pragma unroll
    for (int off = 1; off < 16; off <<= 1) {
#pragma unroll
      for (int r = 0; r < 4; ++r) {
        s[r] += __shfl_xor(s[r], off, 64);
        sq[r] += __shfl_xor(sq[r], off, 64);
      }
    }
    if (fr == 0) {
#pragma unroll
      for (int r = 0; r < 4; ++r) {
        red[w][fq * 4 + r][0] = s[r];
        red[w][fq * 4 + r][1] = sq[r];
      }
    }
    __syncthreads();
    float mean[4], rsig[4];
#pragma unroll
    for (int r = 0; r < 4; ++r) {
      const int p = fq * 4 + r;
      float ss = 0.f, qq = 0.f;
#pragma unroll
      for (int ww = 0; ww < 8; ++ww) {
        ss += red[ww][p][0];
        qq += red[ww][p][1];
      }
      const float m = ss * (1.f / 512.f);
      mean[r] = m;
      rsig[r] = rsqrtf(qq * (1.f / 512.f) - m * m + 1e-5f);
    }
    __syncthreads();
#pragma unroll
    for (int r = 0; r < 4; ++r) {
      const int srow = (j0 + fq * 4 + r) * S + i;
      const bool ok = srow < L;
#pragma unroll
      for (int nt = 0; nt < 4; ++nt) {
        const float nv = (acc[nt][r] - mean[r]) * rsig[r] * gv[nt] + btv[nt];
        pool[nt][r] += ok ? nv : 0.f;
      }
    }
  }
  const float inv = 1.f / (float)S;
#pragma unroll
  for (int r = 0; r < 4; ++r) {
    const int j = j0 + fq * 4 + r;
    const bool ok = j < new_len;
#pragma unroll
    for (int nt = 0; nt < 4; ++nt)
      pooled_b[(size_t)j * 512 + colbase + nt * 16 + fr] =
          (__bf16)(ok ? pool[nt][r] * inv : 0.f);
  }
}

// =====================================================================
// K+V+Q register GEMM in one launch (z picks operand set); K=512,
// one 16x16 tile per wave, fragments direct from global, no LDS/barriers.
// z==2 (q): M=512 -> only blockIdx.y<8 active.
// =====================================================================
__global__ __launch_bounds__(256) void kvq_reg_gemm_kernel(
    const __bf16* __restrict__ pooled, const __bf16* __restrict__ fusedbf,
    const __bf16* __restrict__ wk_t, const float* __restrict__ bk,
    const __bf16* __restrict__ wv_t, const float* __restrict__ bv,
    const __bf16* __restrict__ wq_t, const float* __restrict__ bq,
    __bf16* __restrict__ kout, __bf16* __restrict__ vout,
    __bf16* __restrict__ qout) {
  const int z = blockIdx.z;
  if (z == 2 && blockIdx.y >= 8) return;
  const __bf16* A = (z == 2) ? fusedbf : pooled;
  const int lda = (z == 2) ? 1024 : 512;
  const __bf16* Wt = (z == 0) ? wk_t : (z == 1) ? wv_t : wq_t;
  const float* bias = (z == 0) ? bk : (z == 1) ? bv : bq;
  __bf16* C = (z == 0) ? kout : (z == 1) ? vout : qout;
  const int t = threadIdx.x, lane = t & 63, w = t >> 6;
  const int n0 = blockIdx.x * 16;
  const int m0 = blockIdx.y * 64 + w * 16;
  const int fr = lane & 15, fq = lane >> 4;
  const __bf16* arow = A + (size_t)(m0 + fr) * lda + fq * 8;
  const __bf16* brow = Wt + (size_t)(n0 + fr) * 512 + fq * 8;
  f32x4 acc = f32x4{0.f, 0.f, 0.f, 0.f};
#pragma unroll
  for (int ks = 0; ks < 16; ++ks) {
    bf16x8 a = *reinterpret_cast<const bf16x8*>(arow + ks * 32);
    bf16x8 b = *reinterpret_cast<const bf16x8*>(brow + ks * 32);
    acc = mfma16(a, b, acc);
  }
  const int col = n0 + fr;
  const float bvv = bias[col];
  const int r0 = m0 + fq * 4;
#pragma unroll
  for (int r = 0; r < 4; ++r)
    C[(size_t)(r0 + r) * 512 + col] = (__bf16)(acc[r] + bvv);
}

// =====================================================================
// CTC head register GEMM: out[512,1296] = fusedbf @ Wt^T + bias (K=1024)
// =====================================================================
__global__ __launch_bounds__(256) void ctc_gemm_kernel(
    const __bf16* __restrict__ A, const __bf16* __restrict__ Wt,
    const float* __restrict__ bias, float* __restrict__ out) {
  const int t = threadIdx.x, lane = t & 63, w = t >> 6;
  const int n0 = blockIdx.x * 16;
  const int m0 = blockIdx.y * 64 + w * 16;
  const int fr = lane & 15, fq = lane >> 4;
  const __bf16* arow = A + (size_t)(m0 + fr) * 1024 + fq * 8;
  const __bf16* brow = Wt + (size_t)(n0 + fr) * 1024 + fq * 8;
  f32x4 acc = f32x4{0.f, 0.f, 0.f, 0.f};
#pragma unroll
  for (int ks = 0; ks < 32; ++ks) {
    bf16x8 a = *reinterpret_cast<const bf16x8*>(arow + ks * 32);
    bf16x8 b = *reinterpret_cast<const bf16x8*>(brow + ks * 32);
    acc = mfma16(a, b, acc);
  }
  const int col = n0 + fr;
  const float bv = bias[col];
  const int r0 = m0 + fq * 4;
#pragma unroll
  for (int r = 0; r < 4; ++r)
    out[(size_t)(r0 + r) * 1296 + col] = acc[r] + bv;
}

// =====================================================================
// Fused attention: one block per (b,h). scores -> softmax -> P in LDS
// -> stage all of V (XOR-swizzled k) -> 16 barrier-free PV sub-steps.
// =====================================================================
__global__ __launch_bounds__(256) void attn_fused_kernel(
    const __bf16* __restrict__ q, const __bf16* __restrict__ k,
    const __bf16* __restrict__ v, const int* __restrict__ lens,
    __bf16* __restrict__ ctx) {
  __shared__ __bf16 Qs[64 * 72];
  __shared__ __bf16 Ps[64 * 520];
  __shared__ __bf16 KVs[64 * 520];
  const int t = threadIdx.x, lane = t & 63, w = t >> 6;
  const int bh = blockIdx.x, b = bh >> 3, h = bh & 7;
  const int L = lens[b];
  const int sdiv = (L + 511) >> 9;
  const int new_len = (L + sdiv - 1) / sdiv;
  const size_t qbase = (size_t)b * 64 * 512 + h * 64;
  const size_t kbase = (size_t)b * 512 * 512 + h * 64;
  const size_t vbase = kbase;
  const int fr = lane & 15, fkq = (lane >> 4) * 8;

#pragma unroll
  for (int rep = 0; rep < 4; ++rep) {
    const int gidx = rep * 256 + t;
    const int row = gidx >> 4, c = (gidx & 15) * 4;
    *reinterpret_cast<bf16x4*>(&Qs[row * 72 + c]) =
        *reinterpret_cast<const bf16x4*>(&q[qbase + (size_t)row * 512 + c]);
  }
  f32x4 acc[32];
#pragma unroll
  for (int nt = 0; nt < 32; ++nt) acc[nt] = f32x4{0.f, 0.f, 0.f, 0.f};
  for (int ks = 0; ks < 2; ++ks) {
    const int k0 = ks * 32;
#pragma unroll
    for (int rep = 0; rep < 16; ++rep) {
      const int gidx = rep * 256 + t;
      const int row = gidx >> 3, c = (gidx & 7) * 4;
      *reinterpret_cast<bf16x4*>(&KVs[row * 40 + c]) =
          *reinterpret_cast<const bf16x4*>(&k[kbase + (size_t)row * 512 + k0 + c]);
    }
    __syncthreads();
    const bf16x8 af =
        *reinterpret_cast<const bf16x8*>(&Qs[(w * 16 + fr) * 72 + k0 + fkq]);
#pragma unroll
    for (int nt = 0; nt < 32; ++nt) {
      bf16x8 bf = *reinterpret_cast<const bf16x8*>(&KVs[(nt * 16 + fr) * 40 + fkq]);
      acc[nt] = mfma16(af, bf, acc[nt]);
    }
    __syncthreads();
  }
  const float scale = 0.125f;
#pragma unroll
  for (int r = 0; r < 4; ++r) {
    float mx = -3.0e38f;
#pragma unroll
    for (int nt = 0; nt < 32; ++nt) {
      const int col = nt * 16 + fr;
      const float sv = acc[nt][r] * scale;
      if (col < new_len) mx = fmaxf(mx, sv);
    }
#pragma unroll
    for (int off = 1; off < 16; off <<= 1) mx = fmaxf(mx, __shfl_xor(mx, off, 64));
    float sum = 0.f;
#pragma unroll
    for (int nt = 0; nt < 32; ++nt) {
      const int col = nt * 16 + fr;
      const float e = (col < new_len) ? __expf(acc[nt][r] * scale - mx) : 0.f;
      acc[nt][r] = e;
      sum += e;
    }
#pragma unroll
    for (int off = 1; off < 16; off <<= 1) sum += __shfl_xor(sum, off, 64);
    const float inv = 1.f / sum;
    const int row = w * 16 + ((lane >> 4) << 2) + r;
#pragma unroll
    for (int nt = 0; nt < 32; ++nt)
      Ps[row * 520 + nt * 16 + fr] = (__bf16)(acc[nt][r] * inv);
  }
  __syncthreads();
  {
    const int d = t & 63;
    const int kc = (t >> 6) * 128;
    const int sw = (d & 7) << 3;
#pragma unroll
    for (int j8 = 0; j8 < 16; ++j8) {
      const int kv0 = kc + j8 * 8;
      bf16x8 tmp;
#pragma unroll
      for (int jj = 0; jj < 8; ++jj)
        tmp[jj] = v[vbase + (size_t)(kv0 + jj) * 512 + d];
      *reinterpret_cast<bf16x8*>(&KVs[d * 520 + (kv0 ^ sw)]) = tmp;
    }
  }
  __syncthreads();
  f32x4 acc2[4];
#pragma unroll
  for (int nt = 0; nt < 4; ++nt) acc2[nt] = f32x4{0.f, 0.f, 0.f, 0.f};
  const int swr = (fr & 7) << 3;
#pragma unroll
  for (int s = 0; s < 16; ++s) {
    const int k0 = s * 32;
    const bf16x8 af =
        *reinterpret_cast<const bf16x8*>(&Ps[(w * 16 + fr) * 520 + k0 + fkq]);
#pragma unroll
    for (int nt = 0; nt < 4; ++nt) {
      bf16x8 bf = *reinterpret_cast<const bf16x8*>(
          &KVs[(nt * 16 + fr) * 520 + ((k0 + fkq) ^ swr)]);
      acc2[nt] = mfma16(af, bf, acc2[nt]);
    }
  }
  const int rq = (lane >> 4) * 4;
  const size_t cbase = (size_t)b * 64 * 512 + h * 64;
#pragma unroll
  for (int nt = 0; nt < 4; ++nt)
#pragma unroll
    for (int r = 0; r < 4; ++r)
      ctx[cbase + (size_t)(w * 16 + rq + r) * 512 + nt * 16 + fr] =
          (__bf16)acc2[nt][r];
}

// =====================================================================
// Fused Wo GEMM + LayerNorm: block = 16 rows x full 512 cols (8 waves,
// wave w owns cols w*64..w*64+63). Register GEMM (K=512, no LDS for
// operands), then row LN via shfl + cross-wave LDS reduce, write bf16
// into fusedbf[:, 512:1024]. Removes the ctxo round-trip + ln launch.
// =====================================================================
__global__ __launch_bounds__(512) void wo_ln_kernel(
    const __bf16* __restrict__ ctxbf, const __bf16* __restrict__ wo_t,
    const float* __restrict__ bo, const float* __restrict__ g,
    const float* __restrict__ bt, __bf16* __restrict__ fusedbf) {
  __shared__ float red[8][16][2];
  const int t = threadIdx.x, lane = t & 63, w = t >> 6;
  const int m0 = blockIdx.x * 16;
  const int fr = lane & 15, fq = lane >> 4;
  const int colbase = w * 64;
  const __bf16* arow = ctxbf + (size_t)(m0 + fr) * 512 + fq * 8;
  f32x4 acc[4];
#pragma unroll
  for (int nt = 0; nt < 4; ++nt) acc[nt] = f32x4{0.f, 0.f, 0.f, 0.f};
#pragma unroll
  for (int ks = 0; ks < 16; ++ks) {
    bf16x8 a = *reinterpret_cast<const bf16x8*>(arow + ks * 32);
#pragma unroll
    for (int nt = 0; nt < 4; ++nt) {
      bf16x8 b = *reinterpret_cast<const bf16x8*>(
          wo_t + (size_t)(colbase + nt * 16 + fr) * 512 + fq * 8 + ks * 32);
      acc[nt] = mfma16(a, b, acc[nt]);
    }
  }
  float gv[4], btv[4];
  float s[4] = {0.f, 0.f, 0.f, 0.f}, sq[4] = {0.f, 0.f, 0.f, 0.f};
#pragma unroll
  for (int nt = 0; nt < 4; ++nt) {
    const int col = colbase + nt * 16 + fr;
    const float bv = bo[col];
    gv[nt] = g[col];
    btv[nt] = bt[col];
#pragma unroll
    for (int r = 0; r < 4; ++r) {
      const float v = acc[nt][r] + bv;
      acc[nt][r] = v;
      s[r] += v;
      sq[r] += v * v;
    }
  }
#pragma unroll
  for (int off = 1; off < 16; off <<= 1) {
#pragma unroll
    for (int r = 0; r < 4; ++r) {
      s[r] += __shfl_xor(s[r], off, 64);
      sq[r] += __shfl_xor(sq[r], off, 64);
    }
  }
  if (fr == 0) {
#pragma unroll
    for (int r = 0; r < 4; ++r) {
      red[w][fq * 4 + r][0] = s[r];
      red[w][fq * 4 + r][1] = sq[r];
    }
  }
  __syncthreads();
#pragma unroll
  for (int r = 0; r < 4; ++r) {
    const int p = fq * 4 + r;
    float ss = 0.f, qq = 0.f;
#pragma unroll
    for (int ww = 0; ww < 8; ++ww) {
      ss += red[ww][p][0];
      qq += red[ww][p][1];
    }
    const float m = ss * (1.f / 512.f);
    const float rs = rsqrtf(qq * (1.f / 512.f) - m * m + 1e-5f);
    __bf16* yrow = fusedbf + (size_t)(m0 + fq * 4 + r) * 1024 + 512;
#pragma unroll
    for (int nt = 0; nt < 4; ++nt) {
      const int col = colbase + nt * 16 + fr;
      yrow[col] = (__bf16)((acc[nt][r] - m) * rs * gv[nt] + btv[nt]);
    }
  }
}

// =====================================================================
// Workspace layout (live ranges by step):
//   ws+ 0.. 1 MB  low      (1-3)
//   ws+ 1.. 2 MB  qbuf bf16 512KB (5-6)
//   ws+ 2.. 3 MB  wtq (1-4)
//   ws+ 3.. 4 MB  fusedbf  (3-8)
//   ws+ 4..28.5   partials bf16 49x512KB (2-3, dead after 3)
//     overlaps:   pooled bf16 ws+4..8   (4-5)
//                 kbuf   bf16 ws+12..16 (5-6)
//                 vbuf   bf16 ws+16..20 (5-6)
//   ws+28..29 MB  ctxbf bf16 512KB (6-7, partials dead)
//   ws+29..31.6   wtc
//   ws+32..34 MB  wq_t/wk_t/wv_t/wo_t bf16 512KB each
// =====================================================================
extern "C" void kernel_launch(void* const* d_in, const int* in_sizes, int n_in,
                              void* d_out, int out_size, void* d_ws,
                              size_t ws_size, hipStream_t stream) {
  const float* images = (const float*)d_in[0];
  const float* qgrids = (const float*)d_in[1];
  const float* keypoints = (const float*)d_in[2];
  const int* qlens = (const int*)d_in[3];
  const float* W_img = (const float*)d_in[4];
  const float* b_img = (const float*)d_in[5];
  const float* W_kp = (const float*)d_in[6];
  const float* b_kp = (const float*)d_in[7];
  const float* g_kp = (const float*)d_in[8];
  const float* bt_kp = (const float*)d_in[9];
  const float* W_qp = (const float*)d_in[10];
  const float* b_qp = (const float*)d_in[11];
  const float* g_qln = (const float*)d_in[12];
  const float* bt_qln = (const float*)d_in[13];
  const float* Wq = (const float*)d_in[14];
  const float* bq = (const float*)d_in[15];
  const float* Wk = (const float*)d_in[16];
  const float* bk = (const float*)d_in[17];
  const float* Wv = (const float*)d_in[18];
  const float* bv = (const float*)d_in[19];
  const float* Wo = (const float*)d_in[20];
  const float* bo = (const float*)d_in[21];
  const float* g_attn = (const float*)d_in[22];
  const float* bt_attn = (const float*)d_in[23];
  const float* W_ctc = (const float*)d_in[24];
  const float* b_ctc = (const float*)d_in[25];
  float* out = (float*)d_out;

  const size_t MB = 1u << 20;
  if (ws_size < 34 * MB) return;
  char* ws = (char*)d_ws;
  float* low = (float*)(ws);
  __bf16* qbuf = (__bf16*)(ws + 1 * MB);
  __bf16* wtq = (__bf16*)(ws + 2 * MB);
  __bf16* fusedbf = (__bf16*)(ws + 3 * MB);
  __bf16* partials = (__bf16*)(ws + 4 * MB);
  __bf16* pooled = (__bf16*)(ws + 4 * MB);
  __bf16* kbuf = (__bf16*)(ws + 12 * MB);
  __bf16* vbuf = (__bf16*)(ws + 16 * MB);
  __bf16* ctxbf = (__bf16*)(ws + 28 * MB);
  __bf16* wtc = (__bf16*)(ws + 29 * MB);
  __bf16* wq_t = (__bf16*)(ws + 32 * MB);
  __bf16* wk_t = (__bf16*)(ws + 32 * MB + 512 * 1024);
  __bf16* wv_t = (__bf16*)(ws + 33 * MB);
  __bf16* wo_t = (__bf16*)(ws + 33 * MB + 512 * 1024);

  // 1) all weight transposes + kp_feat in ONE launch
  prep_kernel<<<3360, 256, 0, stream>>>(W_qp, wtq, Wq, Wk, Wv, Wo, wq_t, wk_t,
                                        wv_t, wo_t, W_ctc, wtc, keypoints,
                                        W_kp, b_kp, g_kp, bt_kp, low);
  // 2) img GEMM partials (split-K=49, BK=64, depth-1, XCD swizzle)
  img_gemm_kernel<<<dim3(4, 4, SPLITK), 512, 0, stream>>>(images, W_img, partials);
  // 3) low += b_img + sum(partials); fusedbf[:, :512] = bf16(low)
  reduce_add_kernel<<<1024, 256, 0, stream>>>(partials, b_img, low, fusedbf);
  // 4) pooled qgrid tokens -> bf16 (partials dead)
  pool_mfma_kernel<<<256, 512, 0, stream>>>(qgrids, qlens, wtq, b_qp, g_qln,
                                            bt_qln, pooled);
  // 5) k + v + q via register GEMM, one launch
  kvq_reg_gemm_kernel<<<dim3(32, 64, 3), 256, 0, stream>>>(
      pooled, fusedbf, wk_t, bk, wv_t, bv, wq_t, bq, kbuf, vbuf, qbuf);
  // 6) fused attention (scores+softmax+PV, P in LDS)
  attn_fused_kernel<<<64, 256, 0, stream>>>(qbuf, kbuf, vbuf, qlens, ctxbf);
  // 7) Wo GEMM + LN fused -> fusedbf[:, 512:]
  wo_ln_kernel<<<32, 512, 0, stream>>>(ctxbf, wo_t, bo, g_attn, bt_attn,
                                       fusedbf);
  // 8) out = fusedbf @ Wt_ctc^T + b_ctc
  ctc_gemm_kernel<<<dim3(81, 8), 256, 0, stream>>>(fusedbf, wtc, b_ctc, out);
}

// Round 14
// 250.478 us; speedup vs baseline: 1.0247x; 1.0247x over previous
//
#include <hip/hip_runtime.h>
#include <hip/hip_bf16.h>

typedef __bf16 bf16x8 __attribute__((ext_vector_type(8)));
typedef __bf16 bf16x4 __attribute__((ext_vector_type(4)));
typedef float f32x4 __attribute__((ext_vector_type(4)));
typedef float f32x2 __attribute__((ext_vector_type(2)));

__device__ __forceinline__ f32x4 mfma16(bf16x8 a, bf16x8 b, f32x4 c) {
  return __builtin_amdgcn_mfma_f32_16x16x32_bf16(a, b, c, 0, 0, 0);
}

__device__ __forceinline__ bf16x8 cvt8(const float* f) {
  bf16x8 r;
#pragma unroll
  for (int i = 0; i < 8; ++i) r[i] = (__bf16)f[i];
  return r;
}

// ---- block reduction helpers (blockDim.x == 256 assumed, 4 waves) ----
__device__ __forceinline__ void blockRed2(float& a, float& b, float* red) {
#pragma unroll
  for (int off = 1; off < 64; off <<= 1) {
    a += __shfl_xor(a, off, 64);
    b += __shfl_xor(b, off, 64);
  }
  const int w = threadIdx.x >> 6;
  if ((threadIdx.x & 63) == 0) { red[w] = a; red[4 + w] = b; }
  __syncthreads();
  a = red[0] + red[1] + red[2] + red[3];
  b = red[4] + red[5] + red[6] + red[7];
  __syncthreads();
}

// =====================================================================
// Stage A: img_feat partials = images_flat(512x37632) @ W_img(37632x512)
// split-K=49, tile 128x128, BK=32, 8 waves, dbuf LDS, DEPTH-3 register
// pipeline, XCD-chunked swizzle. (Proven config: 83us, VGPR 60.
// Falsified alternatives: BK=64 depth-2 spilled (WRITE 84MB, 125us);
// BK=64 depth-1 neutral-worse (86us) -> barrier count is NOT the limiter.)
// =====================================================================
#define IMG_K 37632
#define SPLITK 49
#define STEPS_PER 24  // divisible by 6 (2-buf x 3-set unroll)

__global__ __launch_bounds__(512) void img_gemm_kernel(
    const float* __restrict__ A, const float* __restrict__ B,
    __bf16* __restrict__ partials) {
  __shared__ __bf16 As[2][128 * 40];
  __shared__ __bf16 Bs[2][128 * 40];
  const int t = threadIdx.x;
  const int lane = t & 63;
  const int w = t >> 6;
  const int wr = (w >> 2) * 64;
  const int wc = (w & 3) * 32;
  // XCD-chunked bijective swizzle: 784 blocks = 8 XCDs x 98.
  const int orig = blockIdx.x + (blockIdx.y << 2) + (blockIdx.z << 4);
  const int swz = (orig & 7) * 98 + (orig >> 3);
  const int m0 = ((swz >> 2) & 3) * 128;
  const int n0 = (swz & 3) * 128;
  const int zz = swz >> 4;
  const int step0 = zz * STEPS_PER;

  f32x4 acc[4][2];
#pragma unroll
  for (int i = 0; i < 4; ++i)
#pragma unroll
    for (int j = 0; j < 2; ++j) acc[i][j] = f32x4{0.f, 0.f, 0.f, 0.f};

  const int ar = t >> 2, ak = (t & 3) * 8;
  const int bn = t & 127, bk = (t >> 7) * 8;
  const int fr = lane & 15, fk = (lane >> 4) * 8;

  float r0a[8], r0b[8], r1a[8], r1b[8], r2a[8], r2b[8];
#define IMG_LOAD(AT, BT, K0)                                                \
  do {                                                                      \
    const float* asrc = A + (size_t)(m0 + ar) * IMG_K + (K0) + ak;          \
    f32x4 v0 = *reinterpret_cast<const f32x4*>(asrc);                       \
    f32x4 v1 = *reinterpret_cast<const f32x4*>(asrc + 4);                   \
    AT[0] = v0[0]; AT[1] = v0[1]; AT[2] = v0[2]; AT[3] = v0[3];             \
    AT[4] = v1[0]; AT[5] = v1[1]; AT[6] = v1[2]; AT[7] = v1[3];             \
    const float* bsrc = B + (size_t)((K0) + bk) * 512 + n0 + bn;            \
    _Pragma("unroll") for (int j = 0; j < 8; ++j) BT[j] =                   \
        bsrc[(size_t)j * 512];                                              \
  } while (0)
#define IMG_WRITE(BUF, AT, BT)                                              \
  do {                                                                      \
    *reinterpret_cast<bf16x8*>(&As[BUF][ar * 40 + ak]) = cvt8(AT);          \
    *reinterpret_cast<bf16x8*>(&Bs[BUF][bn * 40 + bk]) = cvt8(BT);          \
  } while (0)
#define IMG_MFMA(BUF)                                                       \
  do {                                                                      \
    bf16x8 af[4], bfr[2];                                                   \
    _Pragma("unroll") for (int i = 0; i < 4; ++i) af[i] =                   \
        *reinterpret_cast<const bf16x8*>(                                   \
            &As[BUF][(wr + i * 16 + fr) * 40 + fk]);                        \
    _Pragma("unroll") for (int j = 0; j < 2; ++j) bfr[j] =                  \
        *reinterpret_cast<const bf16x8*>(                                   \
            &Bs[BUF][(wc + j * 16 + fr) * 40 + fk]);                        \
    _Pragma("unroll") for (int i = 0; i < 4; ++i)                           \
        _Pragma("unroll") for (int j = 0; j < 2; ++j) acc[i][j] =           \
            mfma16(af[i], bfr[j], acc[i][j]);                               \
  } while (0)
#define IMG_STEP(S, BUF, WBUF, LA, LB, WA, WB)                              \
  do {                                                                      \
    if ((S) + 3 < STEPS_PER) IMG_LOAD(LA, LB, (step0 + (S) + 3) * 32);      \
    IMG_MFMA(BUF);                                                          \
    if ((S) + 1 < STEPS_PER) IMG_WRITE(WBUF, WA, WB);                       \
    __syncthreads();                                                        \
  } while (0)

  IMG_LOAD(r0a, r0b, step0 * 32);
  IMG_WRITE(0, r0a, r0b);
  IMG_LOAD(r1a, r1b, (step0 + 1) * 32);
  IMG_LOAD(r2a, r2b, (step0 + 2) * 32);
  __syncthreads();

  for (int s6 = 0; s6 < STEPS_PER; s6 += 6) {
    IMG_STEP(s6 + 0, 0, 1, r0a, r0b, r1a, r1b);
    IMG_STEP(s6 + 1, 1, 0, r1a, r1b, r2a, r2b);
    IMG_STEP(s6 + 2, 0, 1, r2a, r2b, r0a, r0b);
    IMG_STEP(s6 + 3, 1, 0, r0a, r0b, r1a, r1b);
    IMG_STEP(s6 + 4, 0, 1, r1a, r1b, r2a, r2b);
    IMG_STEP(s6 + 5, 1, 0, r2a, r2b, r0a, r0b);
  }
#undef IMG_LOAD
#undef IMG_WRITE
#undef IMG_MFMA
#undef IMG_STEP

  __bf16* P = partials + (size_t)zz * (512 * 512);
  const int rq = (lane >> 4) * 4;
#pragma unroll
  for (int i = 0; i < 4; ++i)
#pragma unroll
    for (int j = 0; j < 2; ++j)
#pragma unroll
      for (int r = 0; r < 4; ++r)
        P[(size_t)(m0 + wr + i * 16 + rq + r) * 512 + (n0 + wc + j * 16 + fr)] =
            (__bf16)acc[i][j][r];
}

// low[base..base+7] += b_img + sum_z partials; vectorized 16B/lane
// (was 2B/lane scalar -- G13). Also writes bf16 copy into fusedbf.
// Grid: 262144/8/256 = 128 blocks.
__global__ __launch_bounds__(256) void reduce_add_kernel(
    const __bf16* __restrict__ partials, const float* __restrict__ b_img,
    float* __restrict__ low, __bf16* __restrict__ fusedbf) {
  const int g = blockIdx.x * 256 + threadIdx.x;
  const int base = g * 8;
  const int col = base & 511;
  float acc[8];
  {
    f32x4 l0 = *reinterpret_cast<const f32x4*>(low + base);
    f32x4 l1 = *reinterpret_cast<const f32x4*>(low + base + 4);
    f32x4 b0 = *reinterpret_cast<const f32x4*>(b_img + col);
    f32x4 b1 = *reinterpret_cast<const f32x4*>(b_img + col + 4);
#pragma unroll
    for (int j = 0; j < 4; ++j) {
      acc[j] = l0[j] + b0[j];
      acc[4 + j] = l1[j] + b1[j];
    }
  }
#pragma unroll
  for (int z = 0; z < SPLITK; ++z) {
    bf16x8 p =
        *reinterpret_cast<const bf16x8*>(partials + (size_t)z * 262144 + base);
#pragma unroll
    for (int j = 0; j < 8; ++j) acc[j] += (float)p[j];
  }
  *reinterpret_cast<f32x4*>(low + base) = f32x4{acc[0], acc[1], acc[2], acc[3]};
  *reinterpret_cast<f32x4*>(low + base + 4) =
      f32x4{acc[4], acc[5], acc[6], acc[7]};
  *reinterpret_cast<bf16x8*>(fusedbf + (size_t)(base >> 9) * 1024 + col) =
      cvt8(acc);
}

// =====================================================================
// kp_feat = LN(relu(keypoints @ W_kp + b_kp)); one block per row (512)
// =====================================================================
__global__ __launch_bounds__(256) void kp_kernel(
    const float* __restrict__ kp, const float* __restrict__ W,
    const float* __restrict__ bias, const float* __restrict__ g,
    const float* __restrict__ bt, float* __restrict__ low) {
  __shared__ float rowv[242];
  __shared__ float red[8];
  const int t = threadIdx.x;
  const size_t roff = (size_t)blockIdx.x * 242;
  if (t < 242) rowv[t] = kp[roff + t];
  __syncthreads();
  const int d0 = t, d1 = t + 256;
  float p0 = bias[d0], p1 = bias[d1];
  for (int kk = 0; kk < 242; ++kk) {
    const float x = rowv[kk];
    p0 = fmaf(x, W[kk * 512 + d0], p0);
    p1 = fmaf(x, W[kk * 512 + d1], p1);
  }
  p0 = fmaxf(p0, 0.f);
  p1 = fmaxf(p1, 0.f);
  float s = p0 + p1, sq = p0 * p0 + p1 * p1;
  blockRed2(s, sq, red);
  const float m = s * (1.f / 512.f);
  const float var = sq * (1.f / 512.f) - m * m;
  const float rs = rsqrtf(var + 1e-5f);
  const size_t off = (size_t)blockIdx.x * 512;
  low[off + d0] = (p0 - m) * rs * g[d0] + bt[d0];
  low[off + d1] = (p1 - m) * rs * g[d1] + bt[d1];
}

// =====================================================================
// W_qp transpose+convert: Wt[col][k] bf16, k padded 242 -> 256 (zeros).
// =====================================================================
__global__ __launch_bounds__(256) void wqp_transpose_kernel(
    const float* __restrict__ W, __bf16* __restrict__ Wt) {
  const int c = blockIdx.x;
  const int t = threadIdx.x;
  Wt[(size_t)c * 256 + t] = (t < 242) ? (__bf16)W[(size_t)t * 512 + c] : (__bf16)0.f;
}

// =====================================================================
// Generic transpose+convert (LDS-tiled): W [NK][NC] f32 -> Wt [NC][NK]
// =====================================================================
__device__ __forceinline__ void wtrans_body(const float* __restrict__ W,
                                            __bf16* __restrict__ Wt, int NC,
                                            int NK, int bx, int by) {
  __shared__ float T[32][33];
  const int t = threadIdx.x;
  const int c0 = bx * 32;
  const int k0 = by * 32;
#pragma unroll
  for (int r = 0; r < 4; ++r) {
    const int idx = r * 256 + t;
    const int i = idx >> 5, j = idx & 31;
    const int c = c0 + j;
    T[i][j] = (c < NC) ? W[(size_t)(k0 + i) * NC + c] : 0.f;
  }
  __syncthreads();
#pragma unroll
  for (int r = 0; r < 4; ++r) {
    const int idx = r * 256 + t;
    const int i = idx >> 5, j = idx & 31;
    const int c = c0 + i;
    if (c < NC) Wt[(size_t)c * NK + k0 + j] = (__bf16)T[j][i];
  }
}

__global__ __launch_bounds__(256) void wtrans_kernel(
    const float* __restrict__ W, __bf16* __restrict__ Wt, int NC, int NK) {
  wtrans_body(W, Wt, NC, NK, blockIdx.x, blockIdx.y);
}

// Batched 512x512 transpose for Wq/Wk/Wv/Wo (one launch, z picks matrix)
__global__ __launch_bounds__(256) void wtrans4_kernel(
    const float* __restrict__ W0, const float* __restrict__ W1,
    const float* __restrict__ W2, const float* __restrict__ W3,
    __bf16* __restrict__ T0, __bf16* __restrict__ T1,
    __bf16* __restrict__ T2, __bf16* __restrict__ T3) {
  const float* W = (blockIdx.z == 0) ? W0 : (blockIdx.z == 1) ? W1
                   : (blockIdx.z == 2) ? W2 : W3;
  __bf16* Wt = (blockIdx.z == 0) ? T0 : (blockIdx.z == 1) ? T1
               : (blockIdx.z == 2) ? T2 : T3;
  wtrans_body(W, Wt, 512, 512, blockIdx.x, blockIdx.y);
}

// =====================================================================
// Fused MFMA pooling: pooled = pool_mean(LN(qgrids @ W_qp + b_qp)) bf16
// =====================================================================
__global__ __launch_bounds__(512) void pool_mfma_kernel(
    const float* __restrict__ qgrids, const int* __restrict__ lens,
    const __bf16* __restrict__ Wt, const float* __restrict__ bias,
    const float* __restrict__ g, const float* __restrict__ bt,
    __bf16* __restrict__ pooled) {
  __shared__ float red[8][16][2];
  const int t = threadIdx.x, lane = t & 63, w = t >> 6;
  const int b = blockIdx.x >> 5;
  const int j0 = (blockIdx.x & 31) * 16;
  const int L = lens[b];
  int S = (L + 511) >> 9;
  if (S < 1) S = 1;
  const int new_len = (L + S - 1) / S;
  const float* qg_b = qgrids + (size_t)b * 4096 * 242;
  __bf16* pooled_b = pooled + (size_t)b * 512 * 512;

  const int fr = lane & 15;
  const int fq = lane >> 4;
  const int fkq = fq * 8;
  const int colbase = w * 64;

  float biasv[4], gv[4], btv[4];
#pragma unroll
  for (int nt = 0; nt < 4; ++nt) {
    const int col = colbase + nt * 16 + fr;
    biasv[nt] = bias[col];
    gv[nt] = g[col];
    btv[nt] = bt[col];
  }

  f32x4 pool[4];
#pragma unroll
  for (int nt = 0; nt < 4; ++nt) pool[nt] = f32x4{0.f, 0.f, 0.f, 0.f};

  for (int i = 0; i < S; ++i) {
    const int arow = (j0 + fr) * S + i;
    const float* asrc = qg_b + (size_t)arow * 242;
    f32x4 acc[4];
#pragma unroll
    for (int nt = 0; nt < 4; ++nt) acc[nt] = f32x4{0.f, 0.f, 0.f, 0.f};
#pragma unroll
    for (int ks = 0; ks < 8; ++ks) {
      bf16x8 af;
      if (ks < 7) {
        float tmp[8];
#pragma unroll
        for (int p2 = 0; p2 < 4; ++p2) {
          f32x2 v = *reinterpret_cast<const f32x2*>(asrc + ks * 32 + fkq + p2 * 2);
          tmp[p2 * 2] = v[0];
          tmp[p2 * 2 + 1] = v[1];
        }
        af = cvt8(tmp);
      } else {
        float tmp[8];
#pragma unroll
        for (int jj = 0; jj < 8; ++jj) {
          const int kk = 224 + fkq + jj;
          tmp[jj] = (kk < 242) ? asrc[kk] : 0.f;
        }
        af = cvt8(tmp);
      }
      const __bf16* wt = Wt + ks * 32 + fkq;
#pragma unroll
      for (int nt = 0; nt < 4; ++nt) {
        bf16x8 bfv = *reinterpret_cast<const bf16x8*>(
            wt + (size_t)(colbase + nt * 16 + fr) * 256);
        acc[nt] = mfma16(af, bfv, acc[nt]);
      }
    }
    float s[4] = {0.f, 0.f, 0.f, 0.f}, sq[4] = {0.f, 0.f, 0.f, 0.f};
#pragma unroll
    for (int nt = 0; nt < 4; ++nt) {
#pragma unroll
      for (int r = 0; r < 4; ++r) {
        const float v = acc[nt][r] + biasv[nt];
        acc[nt][r] = v;
        s[r] += v;
        sq[r] += v * v;
      }
    }
#pragma unroll
    for (int off = 1; off < 16; off <<= 1) {
#pragma unroll
      for (int r = 0; r < 4; ++r) {
        s[r] += __shfl_xor(s[r], off, 64);
        sq[r] += __shfl_xor(sq[r], off, 64);
      }
    }
    if (fr == 0) {
#pragma unroll
      for (int r = 0; r < 4; ++r) {
        red[w][fq * 4 + r][0] = s[r];
        red[w][fq * 4 + r][1] = sq[r];
      }
    }
    __syncthreads();
    float mean[4], rsig[4];
#pragma unroll
    for (int r = 0; r < 4; ++r) {
      const int p = fq * 4 + r;
      float ss = 0.f, qq = 0.f;
#pragma unroll
      for (int ww = 0; ww < 8; ++ww) {
        ss += red[ww][p][0];
        qq += red[ww][p][1];
      }
      const float m = ss * (1.f / 512.f);
      mean[r] = m;
      rsig[r] = rsqrtf(qq * (1.f / 512.f) - m * m + 1e-5f);
    }
    __syncthreads();
#pragma unroll
    for (int r = 0; r < 4; ++r) {
      const int srow = (j0 + fq * 4 + r) * S + i;
      const bool ok = srow < L;
#pragma unroll
      for (int nt = 0; nt < 4; ++nt) {
        const float nv = (acc[nt][r] - mean[r]) * rsig[r] * gv[nt] + btv[nt];
        pool[nt][r] += ok ? nv : 0.f;
      }
    }
  }
  const float inv = 1.f / (float)S;
#pragma unroll
  for (int r = 0; r < 4; ++r) {
    const int j = j0 + fq * 4 + r;
    const bool ok = j < new_len;
#pragma unroll
    for (int nt = 0; nt < 4; ++nt)
      pooled_b[(size_t)j * 512 + colbase + nt * 16 + fr] =
          (__bf16)(ok ? pool[nt][r] * inv : 0.f);
  }
}

// =====================================================================
// Register GEMM, K=512: one 16x16 tile per wave, no LDS, no barriers.
// =====================================================================
template <typename OutT>
__global__ __launch_bounds__(256) void reg_gemm512_kernel(
    const __bf16* __restrict__ A, int lda, const __bf16* __restrict__ Wt,
    const float* __restrict__ bias, OutT* __restrict__ C, int ldc) {
  const int t = threadIdx.x, lane = t & 63, w = t >> 6;
  const int n0 = blockIdx.x * 16;
  const int m0 = blockIdx.y * 64 + w * 16;
  const int fr = lane & 15, fq = lane >> 4;
  const __bf16* arow = A + (size_t)(m0 + fr) * lda + fq * 8;
  const __bf16* brow = Wt + (size_t)(n0 + fr) * 512 + fq * 8;
  f32x4 acc = f32x4{0.f, 0.f, 0.f, 0.f};
#pragma unroll
  for (int ks = 0; ks < 16; ++ks) {
    bf16x8 a = *reinterpret_cast<const bf16x8*>(arow + ks * 32);
    bf16x8 b = *reinterpret_cast<const bf16x8*>(brow + ks * 32);
    acc = mfma16(a, b, acc);
  }
  const int col = n0 + fr;
  const float bv = bias[col];
  const int r0 = m0 + fq * 4;
#pragma unroll
  for (int r = 0; r < 4; ++r)
    C[(size_t)(r0 + r) * ldc + col] = (OutT)(acc[r] + bv);
}

// K+V in one launch (blockIdx.z picks weight/bias/output)
__global__ __launch_bounds__(256) void kv_reg_gemm_kernel(
    const __bf16* __restrict__ A, const __bf16* __restrict__ wk_t,
    const float* __restrict__ bk, const __bf16* __restrict__ wv_t,
    const float* __restrict__ bv, __bf16* __restrict__ kout,
    __bf16* __restrict__ vout) {
  const __bf16* Wt = blockIdx.z ? wv_t : wk_t;
  const float* bias = blockIdx.z ? bv : bk;
  __bf16* C = blockIdx.z ? vout : kout;
  const int t = threadIdx.x, lane = t & 63, w = t >> 6;
  const int n0 = blockIdx.x * 16;
  const int m0 = blockIdx.y * 64 + w * 16;
  const int fr = lane & 15, fq = lane >> 4;
  const __bf16* arow = A + (size_t)(m0 + fr) * 512 + fq * 8;
  const __bf16* brow = Wt + (size_t)(n0 + fr) * 512 + fq * 8;
  f32x4 acc = f32x4{0.f, 0.f, 0.f, 0.f};
#pragma unroll
  for (int ks = 0; ks < 16; ++ks) {
    bf16x8 a = *reinterpret_cast<const bf16x8*>(arow + ks * 32);
    bf16x8 b = *reinterpret_cast<const bf16x8*>(brow + ks * 32);
    acc = mfma16(a, b, acc);
  }
  const int col = n0 + fr;
  const float bvv = bias[col];
  const int r0 = m0 + fq * 4;
#pragma unroll
  for (int r = 0; r < 4; ++r)
    C[(size_t)(r0 + r) * 512 + col] = (__bf16)(acc[r] + bvv);
}

// =====================================================================
// CTC head register GEMM: out[512,1296] = fusedbf @ Wt^T + bias (K=1024)
// =====================================================================
__global__ __launch_bounds__(256) void ctc_gemm_kernel(
    const __bf16* __restrict__ A, const __bf16* __restrict__ Wt,
    const float* __restrict__ bias, float* __restrict__ out) {
  const int t = threadIdx.x, lane = t & 63, w = t >> 6;
  const int n0 = blockIdx.x * 16;
  const int m0 = blockIdx.y * 64 + w * 16;
  const int fr = lane & 15, fq = lane >> 4;
  const __bf16* arow = A + (size_t)(m0 + fr) * 1024 + fq * 8;
  const __bf16* brow = Wt + (size_t)(n0 + fr) * 1024 + fq * 8;
  f32x4 acc = f32x4{0.f, 0.f, 0.f, 0.f};
#pragma unroll
  for (int ks = 0; ks < 32; ++ks) {
    bf16x8 a = *reinterpret_cast<const bf16x8*>(arow + ks * 32);
    bf16x8 b = *reinterpret_cast<const bf16x8*>(brow + ks * 32);
    acc = mfma16(a, b, acc);
  }
  const int col = n0 + fr;
  const float bv = bias[col];
  const int r0 = m0 + fq * 4;
#pragma unroll
  for (int r = 0; r < 4; ++r)
    out[(size_t)(r0 + r) * 1296 + col] = acc[r] + bv;
}

// =====================================================================
// Fused attention: one block per (b,h). scores -> softmax -> P in LDS
// -> stage all of V (XOR-swizzled k) -> 16 barrier-free PV sub-steps.
// =====================================================================
__global__ __launch_bounds__(256) void attn_fused_kernel(
    const __bf16* __restrict__ q, const __bf16* __restrict__ k,
    const __bf16* __restrict__ v, const int* __restrict__ lens,
    __bf16* __restrict__ ctx) {
  __shared__ __bf16 Qs[64 * 72];
  __shared__ __bf16 Ps[64 * 520];
  __shared__ __bf16 KVs[64 * 520];
  const int t = threadIdx.x, lane = t & 63, w = t >> 6;
  const int bh = blockIdx.x, b = bh >> 3, h = bh & 7;
  const int L = lens[b];
  const int sdiv = (L + 511) >> 9;
  const int new_len = (L + sdiv - 1) / sdiv;
  const size_t qbase = (size_t)b * 64 * 512 + h * 64;
  const size_t kbase = (size_t)b * 512 * 512 + h * 64;
  const size_t vbase = kbase;
  const int fr = lane & 15, fkq = (lane >> 4) * 8;

#pragma unroll
  for (int rep = 0; rep < 4; ++rep) {
    const int gidx = rep * 256 + t;
    const int row = gidx >> 4, c = (gidx & 15) * 4;
    *reinterpret_cast<bf16x4*>(&Qs[row * 72 + c]) =
        *reinterpret_cast<const bf16x4*>(&q[qbase + (size_t)row * 512 + c]);
  }
  f32x4 acc[32];
#pragma unroll
  for (int nt = 0; nt < 32; ++nt) acc[nt] = f32x4{0.f, 0.f, 0.f, 0.f};
  for (int ks = 0; ks < 2; ++ks) {
    const int k0 = ks * 32;
#pragma unroll
    for (int rep = 0; rep < 16; ++rep) {
      const int gidx = rep * 256 + t;
      const int row = gidx >> 3, c = (gidx & 7) * 4;
      *reinterpret_cast<bf16x4*>(&KVs[row * 40 + c]) =
          *reinterpret_cast<const bf16x4*>(&k[kbase + (size_t)row * 512 + k0 + c]);
    }
    __syncthreads();
    const bf16x8 af =
        *reinterpret_cast<const bf16x8*>(&Qs[(w * 16 + fr) * 72 + k0 + fkq]);
#pragma unroll
    for (int nt = 0; nt < 32; ++nt) {
      bf16x8 bf = *reinterpret_cast<const bf16x8*>(&KVs[(nt * 16 + fr) * 40 + fkq]);
      acc[nt] = mfma16(af, bf, acc[nt]);
    }
    __syncthreads();
  }
  const float scale = 0.125f;
#pragma unroll
  for (int r = 0; r < 4; ++r) {
    float mx = -3.0e38f;
#pragma unroll
    for (int nt = 0; nt < 32; ++nt) {
      const int col = nt * 16 + fr;
      const float sv = acc[nt][r] * scale;
      if (col < new_len) mx = fmaxf(mx, sv);
    }
#pragma unroll
    for (int off = 1; off < 16; off <<= 1) mx = fmaxf(mx, __shfl_xor(mx, off, 64));
    float sum = 0.f;
#pragma unroll
    for (int nt = 0; nt < 32; ++nt) {
      const int col = nt * 16 + fr;
      const float e = (col < new_len) ? __expf(acc[nt][r] * scale - mx) : 0.f;
      acc[nt][r] = e;
      sum += e;
    }
#pragma unroll
    for (int off = 1; off < 16; off <<= 1) sum += __shfl_xor(sum, off, 64);
    const float inv = 1.f / sum;
    const int row = w * 16 + ((lane >> 4) << 2) + r;
#pragma unroll
    for (int nt = 0; nt < 32; ++nt)
      Ps[row * 520 + nt * 16 + fr] = (__bf16)(acc[nt][r] * inv);
  }
  __syncthreads();
  {
    const int d = t & 63;
    const int kc = (t >> 6) * 128;
    const int sw = (d & 7) << 3;
#pragma unroll
    for (int j8 = 0; j8 < 16; ++j8) {
      const int kv0 = kc + j8 * 8;
      bf16x8 tmp;
#pragma unroll
      for (int jj = 0; jj < 8; ++jj)
        tmp[jj] = v[vbase + (size_t)(kv0 + jj) * 512 + d];
      *reinterpret_cast<bf16x8*>(&KVs[d * 520 + (kv0 ^ sw)]) = tmp;
    }
  }
  __syncthreads();
  f32x4 acc2[4];
#pragma unroll
  for (int nt = 0; nt < 4; ++nt) acc2[nt] = f32x4{0.f, 0.f, 0.f, 0.f};
  const int swr = (fr & 7) << 3;
#pragma unroll
  for (int s = 0; s < 16; ++s) {
    const int k0 = s * 32;
    const bf16x8 af =
        *reinterpret_cast<const bf16x8*>(&Ps[(w * 16 + fr) * 520 + k0 + fkq]);
#pragma unroll
    for (int nt = 0; nt < 4; ++nt) {
      bf16x8 bf = *reinterpret_cast<const bf16x8*>(
          &KVs[(nt * 16 + fr) * 520 + ((k0 + fkq) ^ swr)]);
      acc2[nt] = mfma16(af, bf, acc2[nt]);
    }
  }
  const int rq = (lane >> 4) * 4;
  const size_t cbase = (size_t)b * 64 * 512 + h * 64;
#pragma unroll
  for (int nt = 0; nt < 4; ++nt)
#pragma unroll
    for (int r = 0; r < 4; ++r)
      ctx[cbase + (size_t)(w * 16 + rq + r) * 512 + nt * 16 + fr] =
          (__bf16)acc2[nt][r];
}

// LayerNorm over rows of 512, bf16 output into fusedbf[:, 512:1024]
__global__ __launch_bounds__(256) void ln_bf16_kernel(
    const float* __restrict__ x, const float* __restrict__ g,
    const float* __restrict__ bt, __bf16* __restrict__ ybf) {
  __shared__ float red[8];
  const int t = threadIdx.x;
  const size_t off = (size_t)blockIdx.x * 512;
  const float a = x[off + t], b2 = x[off + t + 256];
  float s = a + b2, sq = a * a + b2 * b2;
  blockRed2(s, sq, red);
  const float m = s * (1.f / 512.f);
  const float var = sq * (1.f / 512.f) - m * m;
  const float rs = rsqrtf(var + 1e-5f);
  __bf16* yrow = ybf + (size_t)blockIdx.x * 1024;
  yrow[t] = (__bf16)((a - m) * rs * g[t] + bt[t]);
  yrow[t + 256] = (__bf16)((b2 - m) * rs * g[t + 256] + bt[t + 256]);
}

// =====================================================================
// Workspace layout (live ranges by step):
//   ws+ 0.. 1 MB  low      (2-6)
//   ws+ 1.. 2 MB  qbuf bf16 512KB (6-7)
//   ws+ 2.. 3 MB  wtq (0-4) then ctxo f32 (8)
//   ws+ 3.. 4 MB  fusedbf  (3-9)
//   ws+ 4..28.5   partials bf16 49x512KB (1-3, dead after 3)
//     overlaps:   pooled bf16 ws+4..8   (4-5)
//                 kbuf   bf16 ws+12..16 (5-7)
//                 vbuf   bf16 ws+16..20 (5-7)
//   ws+28..29 MB  ctxbf bf16 512KB (7-8, partials dead)
//   ws+29..31.6   wtc
//   ws+32..34 MB  wq_t/wk_t/wv_t/wo_t bf16 512KB each
// =====================================================================
extern "C" void kernel_launch(void* const* d_in, const int* in_sizes, int n_in,
                              void* d_out, int out_size, void* d_ws,
                              size_t ws_size, hipStream_t stream) {
  const float* images = (const float*)d_in[0];
  const float* qgrids = (const float*)d_in[1];
  const float* keypoints = (const float*)d_in[2];
  const int* qlens = (const int*)d_in[3];
  const float* W_img = (const float*)d_in[4];
  const float* b_img = (const float*)d_in[5];
  const float* W_kp = (const float*)d_in[6];
  const float* b_kp = (const float*)d_in[7];
  const float* g_kp = (const float*)d_in[8];
  const float* bt_kp = (const float*)d_in[9];
  const float* W_qp = (const float*)d_in[10];
  const float* b_qp = (const float*)d_in[11];
  const float* g_qln = (const float*)d_in[12];
  const float* bt_qln = (const float*)d_in[13];
  const float* Wq = (const float*)d_in[14];
  const float* bq = (const float*)d_in[15];
  const float* Wk = (const float*)d_in[16];
  const float* bk = (const float*)d_in[17];
  const float* Wv = (const float*)d_in[18];
  const float* bv = (const float*)d_in[19];
  const float* Wo = (const float*)d_in[20];
  const float* bo = (const float*)d_in[21];
  const float* g_attn = (const float*)d_in[22];
  const float* bt_attn = (const float*)d_in[23];
  const float* W_ctc = (const float*)d_in[24];
  const float* b_ctc = (const float*)d_in[25];
  float* out = (float*)d_out;

  const size_t MB = 1u << 20;
  if (ws_size < 34 * MB) return;
  char* ws = (char*)d_ws;
  float* low = (float*)(ws);
  __bf16* qbuf = (__bf16*)(ws + 1 * MB);
  __bf16* wtq = (__bf16*)(ws + 2 * MB);
  float* ctxo = (float*)(ws + 2 * MB);
  __bf16* fusedbf = (__bf16*)(ws + 3 * MB);
  __bf16* partials = (__bf16*)(ws + 4 * MB);
  __bf16* pooled = (__bf16*)(ws + 4 * MB);
  __bf16* kbuf = (__bf16*)(ws + 12 * MB);
  __bf16* vbuf = (__bf16*)(ws + 16 * MB);
  __bf16* ctxbf = (__bf16*)(ws + 28 * MB);
  __bf16* wtc = (__bf16*)(ws + 29 * MB);
  __bf16* wq_t = (__bf16*)(ws + 32 * MB);
  __bf16* wk_t = (__bf16*)(ws + 32 * MB + 512 * 1024);
  __bf16* wv_t = (__bf16*)(ws + 33 * MB);
  __bf16* wo_t = (__bf16*)(ws + 33 * MB + 512 * 1024);

  // 0) weight transposes
  wqp_transpose_kernel<<<512, 256, 0, stream>>>(W_qp, wtq);
  wtrans4_kernel<<<dim3(16, 16, 4), 256, 0, stream>>>(Wq, Wk, Wv, Wo, wq_t,
                                                      wk_t, wv_t, wo_t);
  wtrans_kernel<<<dim3(41, 32), 256, 0, stream>>>(W_ctc, wtc, 1296, 1024);
  // 1) img GEMM partials (split-K=49, BK=32, depth-3, XCD swizzle)
  img_gemm_kernel<<<dim3(4, 4, SPLITK), 512, 0, stream>>>(images, W_img, partials);
  // 2) kp_feat -> low
  kp_kernel<<<512, 256, 0, stream>>>(keypoints, W_kp, b_kp, g_kp, bt_kp, low);
  // 3) low += b_img + sum(partials); fusedbf[:, :512] = bf16(low)
  //    (vectorized: 16B/lane, 128 blocks)
  reduce_add_kernel<<<128, 256, 0, stream>>>(partials, b_img, low, fusedbf);
  // 4) pooled qgrid tokens -> bf16
  pool_mfma_kernel<<<256, 512, 0, stream>>>(qgrids, qlens, wtq, b_qp, g_qln,
                                            bt_qln, pooled);
  // 5) k + v via register GEMM, one launch
  kv_reg_gemm_kernel<<<dim3(32, 64, 2), 256, 0, stream>>>(pooled, wk_t, bk,
                                                          wv_t, bv, kbuf, vbuf);
  // 6) q via register GEMM (A = fusedbf low-half, lda=1024)
  reg_gemm512_kernel<__bf16><<<dim3(32, 8), 256, 0, stream>>>(
      fusedbf, 1024, wq_t, bq, qbuf, 512);
  // 7) fused attention (scores+softmax+PV, P in LDS)
  attn_fused_kernel<<<64, 256, 0, stream>>>(qbuf, kbuf, vbuf, qlens, ctxbf);
  // 8) ctx @ Wo + bo (f32 out), then LN -> fusedbf[:, 512:]
  reg_gemm512_kernel<float><<<dim3(32, 8), 256, 0, stream>>>(
      ctxbf, 512, wo_t, bo, ctxo, 512);
  ln_bf16_kernel<<<512, 256, 0, stream>>>(ctxo, g_attn, bt_attn, fusedbf + 512);
  // 9) out = fusedbf @ Wt_ctc^T + b_ctc
  ctc_gemm_kernel<<<dim3(81, 8), 256, 0, stream>>>(fusedbf, wtc, b_ctc, out);
}

// Round 15
// 232.809 us; speedup vs baseline: 1.1024x; 1.0759x over previous
//
#include <hip/hip_runtime.h>
#include <hip/hip_bf16.h>

typedef __bf16 bf16x8 __attribute__((ext_vector_type(8)));
typedef __bf16 bf16x4 __attribute__((ext_vector_type(4)));
typedef float f32x4 __attribute__((ext_vector_type(4)));
typedef float f32x2 __attribute__((ext_vector_type(2)));

__device__ __forceinline__ f32x4 mfma16(bf16x8 a, bf16x8 b, f32x4 c) {
  return __builtin_amdgcn_mfma_f32_16x16x32_bf16(a, b, c, 0, 0, 0);
}

__device__ __forceinline__ bf16x8 cvt8(const float* f) {
  bf16x8 r;
#pragma unroll
  for (int i = 0; i < 8; ++i) r[i] = (__bf16)f[i];
  return r;
}

// ---- block reduction helpers (blockDim.x == 256 assumed, 4 waves) ----
__device__ __forceinline__ void blockRed2(float& a, float& b, float* red) {
#pragma unroll
  for (int off = 1; off < 64; off <<= 1) {
    a += __shfl_xor(a, off, 64);
    b += __shfl_xor(b, off, 64);
  }
  const int w = threadIdx.x >> 6;
  if ((threadIdx.x & 63) == 0) { red[w] = a; red[4 + w] = b; }
  __syncthreads();
  a = red[0] + red[1] + red[2] + red[3];
  b = red[4] + red[5] + red[6] + red[7];
  __syncthreads();
}

// =====================================================================
// Stage A: img_feat partials = images_flat(512x37632) @ W_img(37632x512)
// split-K=49, tile 128x128, BK=32, 8 waves, dbuf LDS, DEPTH-3 register
// pipeline, XCD-chunked swizzle. (Proven: 83us, VGPR 60. Falsified:
// BK=64 depth-2 spills; BK=64 depth-1 neutral-worse.)
// =====================================================================
#define IMG_K 37632
#define SPLITK 49
#define STEPS_PER 24  // divisible by 6 (2-buf x 3-set unroll)

__global__ __launch_bounds__(512) void img_gemm_kernel(
    const float* __restrict__ A, const float* __restrict__ B,
    __bf16* __restrict__ partials) {
  __shared__ __bf16 As[2][128 * 40];
  __shared__ __bf16 Bs[2][128 * 40];
  const int t = threadIdx.x;
  const int lane = t & 63;
  const int w = t >> 6;
  const int wr = (w >> 2) * 64;
  const int wc = (w & 3) * 32;
  const int orig = blockIdx.x + (blockIdx.y << 2) + (blockIdx.z << 4);
  const int swz = (orig & 7) * 98 + (orig >> 3);
  const int m0 = ((swz >> 2) & 3) * 128;
  const int n0 = (swz & 3) * 128;
  const int zz = swz >> 4;
  const int step0 = zz * STEPS_PER;

  f32x4 acc[4][2];
#pragma unroll
  for (int i = 0; i < 4; ++i)
#pragma unroll
    for (int j = 0; j < 2; ++j) acc[i][j] = f32x4{0.f, 0.f, 0.f, 0.f};

  const int ar = t >> 2, ak = (t & 3) * 8;
  const int bn = t & 127, bk = (t >> 7) * 8;
  const int fr = lane & 15, fk = (lane >> 4) * 8;

  float r0a[8], r0b[8], r1a[8], r1b[8], r2a[8], r2b[8];
#define IMG_LOAD(AT, BT, K0)                                                \
  do {                                                                      \
    const float* asrc = A + (size_t)(m0 + ar) * IMG_K + (K0) + ak;          \
    f32x4 v0 = *reinterpret_cast<const f32x4*>(asrc);                       \
    f32x4 v1 = *reinterpret_cast<const f32x4*>(asrc + 4);                   \
    AT[0] = v0[0]; AT[1] = v0[1]; AT[2] = v0[2]; AT[3] = v0[3];             \
    AT[4] = v1[0]; AT[5] = v1[1]; AT[6] = v1[2]; AT[7] = v1[3];             \
    const float* bsrc = B + (size_t)((K0) + bk) * 512 + n0 + bn;            \
    _Pragma("unroll") for (int j = 0; j < 8; ++j) BT[j] =                   \
        bsrc[(size_t)j * 512];                                              \
  } while (0)
#define IMG_WRITE(BUF, AT, BT)                                              \
  do {                                                                      \
    *reinterpret_cast<bf16x8*>(&As[BUF][ar * 40 + ak]) = cvt8(AT);          \
    *reinterpret_cast<bf16x8*>(&Bs[BUF][bn * 40 + bk]) = cvt8(BT);          \
  } while (0)
#define IMG_MFMA(BUF)                                                       \
  do {                                                                      \
    bf16x8 af[4], bfr[2];                                                   \
    _Pragma("unroll") for (int i = 0; i < 4; ++i) af[i] =                   \
        *reinterpret_cast<const bf16x8*>(                                   \
            &As[BUF][(wr + i * 16 + fr) * 40 + fk]);                        \
    _Pragma("unroll") for (int j = 0; j < 2; ++j) bfr[j] =                  \
        *reinterpret_cast<const bf16x8*>(                                   \
            &Bs[BUF][(wc + j * 16 + fr) * 40 + fk]);                        \
    _Pragma("unroll") for (int i = 0; i < 4; ++i)                           \
        _Pragma("unroll") for (int j = 0; j < 2; ++j) acc[i][j] =           \
            mfma16(af[i], bfr[j], acc[i][j]);                               \
  } while (0)
#define IMG_STEP(S, BUF, WBUF, LA, LB, WA, WB)                              \
  do {                                                                      \
    if ((S) + 3 < STEPS_PER) IMG_LOAD(LA, LB, (step0 + (S) + 3) * 32);      \
    IMG_MFMA(BUF);                                                          \
    if ((S) + 1 < STEPS_PER) IMG_WRITE(WBUF, WA, WB);                       \
    __syncthreads();                                                        \
  } while (0)

  IMG_LOAD(r0a, r0b, step0 * 32);
  IMG_WRITE(0, r0a, r0b);
  IMG_LOAD(r1a, r1b, (step0 + 1) * 32);
  IMG_LOAD(r2a, r2b, (step0 + 2) * 32);
  __syncthreads();

  for (int s6 = 0; s6 < STEPS_PER; s6 += 6) {
    IMG_STEP(s6 + 0, 0, 1, r0a, r0b, r1a, r1b);
    IMG_STEP(s6 + 1, 1, 0, r1a, r1b, r2a, r2b);
    IMG_STEP(s6 + 2, 0, 1, r2a, r2b, r0a, r0b);
    IMG_STEP(s6 + 3, 1, 0, r0a, r0b, r1a, r1b);
    IMG_STEP(s6 + 4, 0, 1, r1a, r1b, r2a, r2b);
    IMG_STEP(s6 + 5, 1, 0, r2a, r2b, r0a, r0b);
  }
#undef IMG_LOAD
#undef IMG_WRITE
#undef IMG_MFMA
#undef IMG_STEP

  __bf16* P = partials + (size_t)zz * (512 * 512);
  const int rq = (lane >> 4) * 4;
#pragma unroll
  for (int i = 0; i < 4; ++i)
#pragma unroll
    for (int j = 0; j < 2; ++j)
#pragma unroll
      for (int r = 0; r < 4; ++r)
        P[(size_t)(m0 + wr + i * 16 + rq + r) * 512 + (n0 + wc + j * 16 + fr)] =
            (__bf16)acc[i][j][r];
}

// low[idx] = kp_feat(already there) + b_img + sum_z partials[z][idx];
// also writes bf16 copy into fusedbf. (Scalar 1024-block version --
// PROVEN at 238.6us total; 128-block vectorized variant was +12us:
// G13 must not cut grid below CU saturation.)
__global__ __launch_bounds__(256) void reduce_add_kernel(
    const __bf16* __restrict__ partials, const float* __restrict__ b_img,
    float* __restrict__ low, __bf16* __restrict__ fusedbf) {
  const int idx = blockIdx.x * 256 + threadIdx.x;
  float acc = low[idx] + b_img[idx & 511];
#pragma unroll
  for (int z = 0; z < SPLITK; ++z)
    acc += (float)partials[(size_t)z * 262144 + idx];
  low[idx] = acc;
  fusedbf[(size_t)(idx >> 9) * 1024 + (idx & 511)] = (__bf16)acc;
}

// =====================================================================
// prep3: one launch for three same-shape prep passes (1536 blocks):
//   bid <  512: wtq[c][k]   = W_qp^T  bf16, k padded 242->256
//   bid < 1024: wkp_t[c][k] = W_kp^T  bf16, k padded 242->256
//   else:       kpbf[r][k]  = bf16(keypoints[r][k]), padded 242->256
// =====================================================================
__global__ __launch_bounds__(256) void prep3_kernel(
    const float* __restrict__ W_qp, __bf16* __restrict__ wtq,
    const float* __restrict__ W_kp, __bf16* __restrict__ wkp_t,
    const float* __restrict__ kp, __bf16* __restrict__ kpbf) {
  const int bid = blockIdx.x;
  const int t = threadIdx.x;
  if (bid < 512) {
    wtq[(size_t)bid * 256 + t] =
        (t < 242) ? (__bf16)W_qp[(size_t)t * 512 + bid] : (__bf16)0.f;
  } else if (bid < 1024) {
    const int c = bid - 512;
    wkp_t[(size_t)c * 256 + t] =
        (t < 242) ? (__bf16)W_kp[(size_t)t * 512 + c] : (__bf16)0.f;
  } else {
    const int r = bid - 1024;
    kpbf[(size_t)r * 256 + t] =
        (t < 242) ? (__bf16)kp[(size_t)r * 242 + t] : (__bf16)0.f;
  }
}

// kp projection: kptmp = relu(kpbf @ wkp_t^T + b_kp). Register GEMM,
// K=256, one 16x16 tile/wave, grid (32,8) = 256 blocks. (Replaces the
// 242-serial-fmaf scalar kp kernel.)
__global__ __launch_bounds__(256) void kp_gemm_kernel(
    const __bf16* __restrict__ A, const __bf16* __restrict__ Wt,
    const float* __restrict__ bias, float* __restrict__ C) {
  const int t = threadIdx.x, lane = t & 63, w = t >> 6;
  const int n0 = blockIdx.x * 16;
  const int m0 = blockIdx.y * 64 + w * 16;
  const int fr = lane & 15, fq = lane >> 4;
  const __bf16* arow = A + (size_t)(m0 + fr) * 256 + fq * 8;
  const __bf16* brow = Wt + (size_t)(n0 + fr) * 256 + fq * 8;
  f32x4 acc = f32x4{0.f, 0.f, 0.f, 0.f};
#pragma unroll
  for (int ks = 0; ks < 8; ++ks) {
    bf16x8 a = *reinterpret_cast<const bf16x8*>(arow + ks * 32);
    bf16x8 b = *reinterpret_cast<const bf16x8*>(brow + ks * 32);
    acc = mfma16(a, b, acc);
  }
  const int col = n0 + fr;
  const float bv = bias[col];
  const int r0 = m0 + fq * 4;
#pragma unroll
  for (int r = 0; r < 4; ++r)
    C[(size_t)(r0 + r) * 512 + col] = fmaxf(acc[r] + bv, 0.f);
}

// LayerNorm rows of 512 (f32 in -> f32 out into low)
__global__ __launch_bounds__(256) void ln_f32_kernel(
    const float* __restrict__ x, const float* __restrict__ g,
    const float* __restrict__ bt, float* __restrict__ y) {
  __shared__ float red[8];
  const int t = threadIdx.x;
  const size_t off = (size_t)blockIdx.x * 512;
  const float a = x[off + t], b2 = x[off + t + 256];
  float s = a + b2, sq = a * a + b2 * b2;
  blockRed2(s, sq, red);
  const float m = s * (1.f / 512.f);
  const float var = sq * (1.f / 512.f) - m * m;
  const float rs = rsqrtf(var + 1e-5f);
  y[off + t] = (a - m) * rs * g[t] + bt[t];
  y[off + t + 256] = (b2 - m) * rs * g[t + 256] + bt[t + 256];
}

// =====================================================================
// Generic transpose+convert (LDS-tiled): W [NK][NC] f32 -> Wt [NC][NK]
// =====================================================================
__device__ __forceinline__ void wtrans_body(const float* __restrict__ W,
                                            __bf16* __restrict__ Wt, int NC,
                                            int NK, int bx, int by) {
  __shared__ float T[32][33];
  const int t = threadIdx.x;
  const int c0 = bx * 32;
  const int k0 = by * 32;
#pragma unroll
  for (int r = 0; r < 4; ++r) {
    const int idx = r * 256 + t;
    const int i = idx >> 5, j = idx & 31;
    const int c = c0 + j;
    T[i][j] = (c < NC) ? W[(size_t)(k0 + i) * NC + c] : 0.f;
  }
  __syncthreads();
#pragma unroll
  for (int r = 0; r < 4; ++r) {
    const int idx = r * 256 + t;
    const int i = idx >> 5, j = idx & 31;
    const int c = c0 + i;
    if (c < NC) Wt[(size_t)c * NK + k0 + j] = (__bf16)T[j][i];
  }
}

__global__ __launch_bounds__(256) void wtrans_kernel(
    const float* __restrict__ W, __bf16* __restrict__ Wt, int NC, int NK) {
  wtrans_body(W, Wt, NC, NK, blockIdx.x, blockIdx.y);
}

// Batched 512x512 transpose for Wq/Wk/Wv/Wo (one launch, z picks matrix)
__global__ __launch_bounds__(256) void wtrans4_kernel(
    const float* __restrict__ W0, const float* __restrict__ W1,
    const float* __restrict__ W2, const float* __restrict__ W3,
    __bf16* __restrict__ T0, __bf16* __restrict__ T1,
    __bf16* __restrict__ T2, __bf16* __restrict__ T3) {
  const float* W = (blockIdx.z == 0) ? W0 : (blockIdx.z == 1) ? W1
                   : (blockIdx.z == 2) ? W2 : W3;
  __bf16* Wt = (blockIdx.z == 0) ? T0 : (blockIdx.z == 1) ? T1
               : (blockIdx.z == 2) ? T2 : T3;
  wtrans_body(W, Wt, 512, 512, blockIdx.x, blockIdx.y);
}

// =====================================================================
// Fused MFMA pooling: pooled = pool_mean(LN(qgrids @ W_qp + b_qp)) bf16
// =====================================================================
__global__ __launch_bounds__(512) void pool_mfma_kernel(
    const float* __restrict__ qgrids, const int* __restrict__ lens,
    const __bf16* __restrict__ Wt, const float* __restrict__ bias,
    const float* __restrict__ g, const float* __restrict__ bt,
    __bf16* __restrict__ pooled) {
  __shared__ float red[8][16][2];
  const int t = threadIdx.x, lane = t & 63, w = t >> 6;
  const int b = blockIdx.x >> 5;
  const int j0 = (blockIdx.x & 31) * 16;
  const int L = lens[b];
  int S = (L + 511) >> 9;
  if (S < 1) S = 1;
  const int new_len = (L + S - 1) / S;
  const float* qg_b = qgrids + (size_t)b * 4096 * 242;
  __bf16* pooled_b = pooled + (size_t)b * 512 * 512;

  const int fr = lane & 15;
  const int fq = lane >> 4;
  const int fkq = fq * 8;
  const int colbase = w * 64;

  float biasv[4], gv[4], btv[4];
#pragma unroll
  for (int nt = 0; nt < 4; ++nt) {
    const int col = colbase + nt * 16 + fr;
    biasv[nt] = bias[col];
    gv[nt] = g[col];
    btv[nt] = bt[col];
  }

  f32x4 pool[4];
#pragma unroll
  for (int nt = 0; nt < 4; ++nt) pool[nt] = f32x4{0.f, 0.f, 0.f, 0.f};

  for (int i = 0; i < S; ++i) {
    const int arow = (j0 + fr) * S + i;
    const float* asrc = qg_b + (size_t)arow * 242;
    f32x4 acc[4];
#pragma unroll
    for (int nt = 0; nt < 4; ++nt) acc[nt] = f32x4{0.f, 0.f, 0.f, 0.f};
#pragma unroll
    for (int ks = 0; ks < 8; ++ks) {
      bf16x8 af;
      if (ks < 7) {
        float tmp[8];
#pragma unroll
        for (int p2 = 0; p2 < 4; ++p2) {
          f32x2 v = *reinterpret_cast<const f32x2*>(asrc + ks * 32 + fkq + p2 * 2);
          tmp[p2 * 2] = v[0];
          tmp[p2 * 2 + 1] = v[1];
        }
        af = cvt8(tmp);
      } else {
        float tmp[8];
#pragma unroll
        for (int jj = 0; jj < 8; ++jj) {
          const int kk = 224 + fkq + jj;
          tmp[jj] = (kk < 242) ? asrc[kk] : 0.f;
        }
        af = cvt8(tmp);
      }
      const __bf16* wt = Wt + ks * 32 + fkq;
#pragma unroll
      for (int nt = 0; nt < 4; ++nt) {
        bf16x8 bfv = *reinterpret_cast<const bf16x8*>(
            wt + (size_t)(colbase + nt * 16 + fr) * 256);
        acc[nt] = mfma16(af, bfv, acc[nt]);
      }
    }
    float s[4] = {0.f, 0.f, 0.f, 0.f}, sq[4] = {0.f, 0.f, 0.f, 0.f};
#pragma unroll
    for (int nt = 0; nt < 4; ++nt) {
#pragma unroll
      for (int r = 0; r < 4; ++r) {
        const float v = acc[nt][r] + biasv[nt];
        acc[nt][r] = v;
        s[r] += v;
        sq[r] += v * v;
      }
    }
#pragma unroll
    for (int off = 1; off < 16; off <<= 1) {
#pragma unroll
      for (int r = 0; r < 4; ++r) {
        s[r] += __shfl_xor(s[r], off, 64);
        sq[r] += __shfl_xor(sq[r], off, 64);
      }
    }
    if (fr == 0) {
#pragma unroll
      for (int r = 0; r < 4; ++r) {
        red[w][fq * 4 + r][0] = s[r];
        red[w][fq * 4 + r][1] = sq[r];
      }
    }
    __syncthreads();
    float mean[4], rsig[4];
#pragma unroll
    for (int r = 0; r < 4; ++r) {
      const int p = fq * 4 + r;
      float ss = 0.f, qq = 0.f;
#pragma unroll
      for (int ww = 0; ww < 8; ++ww) {
        ss += red[ww][p][0];
        qq += red[ww][p][1];
      }
      const float m = ss * (1.f / 512.f);
      mean[r] = m;
      rsig[r] = rsqrtf(qq * (1.f / 512.f) - m * m + 1e-5f);
    }
    __syncthreads();
#pragma unroll
    for (int r = 0; r < 4; ++r) {
      const int srow = (j0 + fq * 4 + r) * S + i;
      const bool ok = srow < L;
#pragma unroll
      for (int nt = 0; nt < 4; ++nt) {
        const float nv = (acc[nt][r] - mean[r]) * rsig[r] * gv[nt] + btv[nt];
        pool[nt][r] += ok ? nv : 0.f;
      }
    }
  }
  const float inv = 1.f / (float)S;
#pragma unroll
  for (int r = 0; r < 4; ++r) {
    const int j = j0 + fq * 4 + r;
    const bool ok = j < new_len;
#pragma unroll
    for (int nt = 0; nt < 4; ++nt)
      pooled_b[(size_t)j * 512 + colbase + nt * 16 + fr] =
          (__bf16)(ok ? pool[nt][r] * inv : 0.f);
  }
}

// =====================================================================
// Register GEMM, K=512: one 16x16 tile per wave, no LDS, no barriers.
// =====================================================================
template <typename OutT>
__global__ __launch_bounds__(256) void reg_gemm512_kernel(
    const __bf16* __restrict__ A, int lda, const __bf16* __restrict__ Wt,
    const float* __restrict__ bias, OutT* __restrict__ C, int ldc) {
  const int t = threadIdx.x, lane = t & 63, w = t >> 6;
  const int n0 = blockIdx.x * 16;
  const int m0 = blockIdx.y * 64 + w * 16;
  const int fr = lane & 15, fq = lane >> 4;
  const __bf16* arow = A + (size_t)(m0 + fr) * lda + fq * 8;
  const __bf16* brow = Wt + (size_t)(n0 + fr) * 512 + fq * 8;
  f32x4 acc = f32x4{0.f, 0.f, 0.f, 0.f};
#pragma unroll
  for (int ks = 0; ks < 16; ++ks) {
    bf16x8 a = *reinterpret_cast<const bf16x8*>(arow + ks * 32);
    bf16x8 b = *reinterpret_cast<const bf16x8*>(brow + ks * 32);
    acc = mfma16(a, b, acc);
  }
  const int col = n0 + fr;
  const float bv = bias[col];
  const int r0 = m0 + fq * 4;
#pragma unroll
  for (int r = 0; r < 4; ++r)
    C[(size_t)(r0 + r) * ldc + col] = (OutT)(acc[r] + bv);
}

// K+V in one launch (blockIdx.z picks weight/bias/output)
__global__ __launch_bounds__(256) void kv_reg_gemm_kernel(
    const __bf16* __restrict__ A, const __bf16* __restrict__ wk_t,
    const float* __restrict__ bk, const __bf16* __restrict__ wv_t,
    const float* __restrict__ bv, __bf16* __restrict__ kout,
    __bf16* __restrict__ vout) {
  const __bf16* Wt = blockIdx.z ? wv_t : wk_t;
  const float* bias = blockIdx.z ? bv : bk;
  __bf16* C = blockIdx.z ? vout : kout;
  const int t = threadIdx.x, lane = t & 63, w = t >> 6;
  const int n0 = blockIdx.x * 16;
  const int m0 = blockIdx.y * 64 + w * 16;
  const int fr = lane & 15, fq = lane >> 4;
  const __bf16* arow = A + (size_t)(m0 + fr) * 512 + fq * 8;
  const __bf16* brow = Wt + (size_t)(n0 + fr) * 512 + fq * 8;
  f32x4 acc = f32x4{0.f, 0.f, 0.f, 0.f};
#pragma unroll
  for (int ks = 0; ks < 16; ++ks) {
    bf16x8 a = *reinterpret_cast<const bf16x8*>(arow + ks * 32);
    bf16x8 b = *reinterpret_cast<const bf16x8*>(brow + ks * 32);
    acc = mfma16(a, b, acc);
  }
  const int col = n0 + fr;
  const float bvv = bias[col];
  const int r0 = m0 + fq * 4;
#pragma unroll
  for (int r = 0; r < 4; ++r)
    C[(size_t)(r0 + r) * 512 + col] = (__bf16)(acc[r] + bvv);
}

// =====================================================================
// CTC head register GEMM: out[512,1296] = fusedbf @ Wt^T + bias (K=1024)
// =====================================================================
__global__ __launch_bounds__(256) void ctc_gemm_kernel(
    const __bf16* __restrict__ A, const __bf16* __restrict__ Wt,
    const float* __restrict__ bias, float* __restrict__ out) {
  const int t = threadIdx.x, lane = t & 63, w = t >> 6;
  const int n0 = blockIdx.x * 16;
  const int m0 = blockIdx.y * 64 + w * 16;
  const int fr = lane & 15, fq = lane >> 4;
  const __bf16* arow = A + (size_t)(m0 + fr) * 1024 + fq * 8;
  const __bf16* brow = Wt + (size_t)(n0 + fr) * 1024 + fq * 8;
  f32x4 acc = f32x4{0.f, 0.f, 0.f, 0.f};
#pragma unroll
  for (int ks = 0; ks < 32; ++ks) {
    bf16x8 a = *reinterpret_cast<const bf16x8*>(arow + ks * 32);
    bf16x8 b = *reinterpret_cast<const bf16x8*>(brow + ks * 32);
    acc = mfma16(a, b, acc);
  }
  const int col = n0 + fr;
  const float bv = bias[col];
  const int r0 = m0 + fq * 4;
#pragma unroll
  for (int r = 0; r < 4; ++r)
    out[(size_t)(r0 + r) * 1296 + col] = acc[r] + bv;
}

// =====================================================================
// Fused attention: one block per (b,h). scores -> softmax -> P in LDS
// -> stage all of V (XOR-swizzled k) -> 16 barrier-free PV sub-steps.
// =====================================================================
__global__ __launch_bounds__(256) void attn_fused_kernel(
    const __bf16* __restrict__ q, const __bf16* __restrict__ k,
    const __bf16* __restrict__ v, const int* __restrict__ lens,
    __bf16* __restrict__ ctx) {
  __shared__ __bf16 Qs[64 * 72];
  __shared__ __bf16 Ps[64 * 520];
  __shared__ __bf16 KVs[64 * 520];
  const int t = threadIdx.x, lane = t & 63, w = t >> 6;
  const int bh = blockIdx.x, b = bh >> 3, h = bh & 7;
  const int L = lens[b];
  const int sdiv = (L + 511) >> 9;
  const int new_len = (L + sdiv - 1) / sdiv;
  const size_t qbase = (size_t)b * 64 * 512 + h * 64;
  const size_t kbase = (size_t)b * 512 * 512 + h * 64;
  const size_t vbase = kbase;
  const int fr = lane & 15, fkq = (lane >> 4) * 8;

#pragma unroll
  for (int rep = 0; rep < 4; ++rep) {
    const int gidx = rep * 256 + t;
    const int row = gidx >> 4, c = (gidx & 15) * 4;
    *reinterpret_cast<bf16x4*>(&Qs[row * 72 + c]) =
        *reinterpret_cast<const bf16x4*>(&q[qbase + (size_t)row * 512 + c]);
  }
  f32x4 acc[32];
#pragma unroll
  for (int nt = 0; nt < 32; ++nt) acc[nt] = f32x4{0.f, 0.f, 0.f, 0.f};
  for (int ks = 0; ks < 2; ++ks) {
    const int k0 = ks * 32;
#pragma unroll
    for (int rep = 0; rep < 16; ++rep) {
      const int gidx = rep * 256 + t;
      const int row = gidx >> 3, c = (gidx & 7) * 4;
      *reinterpret_cast<bf16x4*>(&KVs[row * 40 + c]) =
          *reinterpret_cast<const bf16x4*>(&k[kbase + (size_t)row * 512 + k0 + c]);
    }
    __syncthreads();
    const bf16x8 af =
        *reinterpret_cast<const bf16x8*>(&Qs[(w * 16 + fr) * 72 + k0 + fkq]);
#pragma unroll
    for (int nt = 0; nt < 32; ++nt) {
      bf16x8 bf = *reinterpret_cast<const bf16x8*>(&KVs[(nt * 16 + fr) * 40 + fkq]);
      acc[nt] = mfma16(af, bf, acc[nt]);
    }
    __syncthreads();
  }
  const float scale = 0.125f;
#pragma unroll
  for (int r = 0; r < 4; ++r) {
    float mx = -3.0e38f;
#pragma unroll
    for (int nt = 0; nt < 32; ++nt) {
      const int col = nt * 16 + fr;
      const float sv = acc[nt][r] * scale;
      if (col < new_len) mx = fmaxf(mx, sv);
    }
#pragma unroll
    for (int off = 1; off < 16; off <<= 1) mx = fmaxf(mx, __shfl_xor(mx, off, 64));
    float sum = 0.f;
#pragma unroll
    for (int nt = 0; nt < 32; ++nt) {
      const int col = nt * 16 + fr;
      const float e = (col < new_len) ? __expf(acc[nt][r] * scale - mx) : 0.f;
      acc[nt][r] = e;
      sum += e;
    }
#pragma unroll
    for (int off = 1; off < 16; off <<= 1) sum += __shfl_xor(sum, off, 64);
    const float inv = 1.f / sum;
    const int row = w * 16 + ((lane >> 4) << 2) + r;
#pragma unroll
    for (int nt = 0; nt < 32; ++nt)
      Ps[row * 520 + nt * 16 + fr] = (__bf16)(acc[nt][r] * inv);
  }
  __syncthreads();
  {
    const int d = t & 63;
    const int kc = (t >> 6) * 128;
    const int sw = (d & 7) << 3;
#pragma unroll
    for (int j8 = 0; j8 < 16; ++j8) {
      const int kv0 = kc + j8 * 8;
      bf16x8 tmp;
#pragma unroll
      for (int jj = 0; jj < 8; ++jj)
        tmp[jj] = v[vbase + (size_t)(kv0 + jj) * 512 + d];
      *reinterpret_cast<bf16x8*>(&KVs[d * 520 + (kv0 ^ sw)]) = tmp;
    }
  }
  __syncthreads();
  f32x4 acc2[4];
#pragma unroll
  for (int nt = 0; nt < 4; ++nt) acc2[nt] = f32x4{0.f, 0.f, 0.f, 0.f};
  const int swr = (fr & 7) << 3;
#pragma unroll
  for (int s = 0; s < 16; ++s) {
    const int k0 = s * 32;
    const bf16x8 af =
        *reinterpret_cast<const bf16x8*>(&Ps[(w * 16 + fr) * 520 + k0 + fkq]);
#pragma unroll
    for (int nt = 0; nt < 4; ++nt) {
      bf16x8 bf = *reinterpret_cast<const bf16x8*>(
          &KVs[(nt * 16 + fr) * 520 + ((k0 + fkq) ^ swr)]);
      acc2[nt] = mfma16(af, bf, acc2[nt]);
    }
  }
  const int rq = (lane >> 4) * 4;
  const size_t cbase = (size_t)b * 64 * 512 + h * 64;
#pragma unroll
  for (int nt = 0; nt < 4; ++nt)
#pragma unroll
    for (int r = 0; r < 4; ++r)
      ctx[cbase + (size_t)(w * 16 + rq + r) * 512 + nt * 16 + fr] =
          (__bf16)acc2[nt][r];
}

// LayerNorm over rows of 512, bf16 output into fusedbf[:, 512:1024]
__global__ __launch_bounds__(256) void ln_bf16_kernel(
    const float* __restrict__ x, const float* __restrict__ g,
    const float* __restrict__ bt, __bf16* __restrict__ ybf) {
  __shared__ float red[8];
  const int t = threadIdx.x;
  const size_t off = (size_t)blockIdx.x * 512;
  const float a = x[off + t], b2 = x[off + t + 256];
  float s = a + b2, sq = a * a + b2 * b2;
  blockRed2(s, sq, red);
  const float m = s * (1.f / 512.f);
  const float var = sq * (1.f / 512.f) - m * m;
  const float rs = rsqrtf(var + 1e-5f);
  __bf16* yrow = ybf + (size_t)blockIdx.x * 1024;
  yrow[t] = (__bf16)((a - m) * rs * g[t] + bt[t]);
  yrow[t + 256] = (__bf16)((b2 - m) * rs * g[t + 256] + bt[t + 256]);
}

// =====================================================================
// Workspace layout (live ranges by step; ws >= 36 MB proven rounds 1-6):
//   ws+ 0.. 1 MB  low      (2-6)
//   ws+ 1.. 2 MB  qbuf bf16 512KB (6-7)
//   ws+ 2.. 3 MB  wtq (0-4) then ctxo f32 (8)
//   ws+ 3.. 4 MB  fusedbf  (3-9)
//   ws+ 4..28.5   partials bf16 49x512KB (1-3, dead after 3)
//     overlaps:   pooled bf16 ws+4..8   (4-5)
//                 kbuf   bf16 ws+12..16 (5-7)
//                 vbuf   bf16 ws+16..20 (5-7)
//   ws+28..29 MB  ctxbf bf16 512KB (7-8, partials dead)
//   ws+29..31.6   wtc
//   ws+32..34 MB  wq_t/wk_t/wv_t/wo_t bf16 512KB each
//   ws+34..34.25  kpbf  bf16 (0-2)
//   ws+34.25-34.5 wkp_t bf16 (0-2)
//   ws+34.5-35.5  kptmp f32  (2-2b)
// =====================================================================
extern "C" void kernel_launch(void* const* d_in, const int* in_sizes, int n_in,
                              void* d_out, int out_size, void* d_ws,
                              size_t ws_size, hipStream_t stream) {
  const float* images = (const float*)d_in[0];
  const float* qgrids = (const float*)d_in[1];
  const float* keypoints = (const float*)d_in[2];
  const int* qlens = (const int*)d_in[3];
  const float* W_img = (const float*)d_in[4];
  const float* b_img = (const float*)d_in[5];
  const float* W_kp = (const float*)d_in[6];
  const float* b_kp = (const float*)d_in[7];
  const float* g_kp = (const float*)d_in[8];
  const float* bt_kp = (const float*)d_in[9];
  const float* W_qp = (const float*)d_in[10];
  const float* b_qp = (const float*)d_in[11];
  const float* g_qln = (const float*)d_in[12];
  const float* bt_qln = (const float*)d_in[13];
  const float* Wq = (const float*)d_in[14];
  const float* bq = (const float*)d_in[15];
  const float* Wk = (const float*)d_in[16];
  const float* bk = (const float*)d_in[17];
  const float* Wv = (const float*)d_in[18];
  const float* bv = (const float*)d_in[19];
  const float* Wo = (const float*)d_in[20];
  const float* bo = (const float*)d_in[21];
  const float* g_attn = (const float*)d_in[22];
  const float* bt_attn = (const float*)d_in[23];
  const float* W_ctc = (const float*)d_in[24];
  const float* b_ctc = (const float*)d_in[25];
  float* out = (float*)d_out;

  const size_t MB = 1u << 20;
  const size_t KB = 1u << 10;
  if (ws_size < 35 * MB + 512 * KB) return;
  char* ws = (char*)d_ws;
  float* low = (float*)(ws);
  __bf16* qbuf = (__bf16*)(ws + 1 * MB);
  __bf16* wtq = (__bf16*)(ws + 2 * MB);
  float* ctxo = (float*)(ws + 2 * MB);
  __bf16* fusedbf = (__bf16*)(ws + 3 * MB);
  __bf16* partials = (__bf16*)(ws + 4 * MB);
  __bf16* pooled = (__bf16*)(ws + 4 * MB);
  __bf16* kbuf = (__bf16*)(ws + 12 * MB);
  __bf16* vbuf = (__bf16*)(ws + 16 * MB);
  __bf16* ctxbf = (__bf16*)(ws + 28 * MB);
  __bf16* wtc = (__bf16*)(ws + 29 * MB);
  __bf16* wq_t = (__bf16*)(ws + 32 * MB);
  __bf16* wk_t = (__bf16*)(ws + 32 * MB + 512 * KB);
  __bf16* wv_t = (__bf16*)(ws + 33 * MB);
  __bf16* wo_t = (__bf16*)(ws + 33 * MB + 512 * KB);
  __bf16* kpbf = (__bf16*)(ws + 34 * MB);
  __bf16* wkp_t = (__bf16*)(ws + 34 * MB + 256 * KB);
  float* kptmp = (float*)(ws + 34 * MB + 512 * KB);

  // 0) prep: wqp^T + wkp^T + kp cast (one launch), qkvo transposes, ctc^T
  prep3_kernel<<<1536, 256, 0, stream>>>(W_qp, wtq, W_kp, wkp_t, keypoints,
                                         kpbf);
  wtrans4_kernel<<<dim3(16, 16, 4), 256, 0, stream>>>(Wq, Wk, Wv, Wo, wq_t,
                                                      wk_t, wv_t, wo_t);
  wtrans_kernel<<<dim3(41, 32), 256, 0, stream>>>(W_ctc, wtc, 1296, 1024);
  // 1) img GEMM partials (split-K=49, BK=32, depth-3, XCD swizzle)
  img_gemm_kernel<<<dim3(4, 4, SPLITK), 512, 0, stream>>>(images, W_img, partials);
  // 2) kp proj via register GEMM (+relu), then LN -> low
  kp_gemm_kernel<<<dim3(32, 8), 256, 0, stream>>>(kpbf, wkp_t, b_kp, kptmp);
  ln_f32_kernel<<<512, 256, 0, stream>>>(kptmp, g_kp, bt_kp, low);
  // 3) low += b_img + sum(partials); fusedbf[:, :512] = bf16(low)
  reduce_add_kernel<<<1024, 256, 0, stream>>>(partials, b_img, low, fusedbf);
  // 4) pooled qgrid tokens -> bf16
  pool_mfma_kernel<<<256, 512, 0, stream>>>(qgrids, qlens, wtq, b_qp, g_qln,
                                            bt_qln, pooled);
  // 5) k + v via register GEMM, one launch
  kv_reg_gemm_kernel<<<dim3(32, 64, 2), 256, 0, stream>>>(pooled, wk_t, bk,
                                                          wv_t, bv, kbuf, vbuf);
  // 6) q via register GEMM (A = fusedbf low-half, lda=1024)
  reg_gemm512_kernel<__bf16><<<dim3(32, 8), 256, 0, stream>>>(
      fusedbf, 1024, wq_t, bq, qbuf, 512);
  // 7) fused attention (scores+softmax+PV, P in LDS)
  attn_fused_kernel<<<64, 256, 0, stream>>>(qbuf, kbuf, vbuf, qlens, ctxbf);
  // 8) ctx @ Wo + bo (f32 out), then LN -> fusedbf[:, 512:]
  reg_gemm512_kernel<float><<<dim3(32, 8), 256, 0, stream>>>(
      ctxbf, 512, wo_t, bo, ctxo, 512);
  ln_bf16_kernel<<<512, 256, 0, stream>>>(ctxo, g_attn, bt_attn, fusedbf + 512);
  // 9) out = fusedbf @ Wt_ctc^T + b_ctc
  ctc_gemm_kernel<<<dim3(81, 8), 256, 0, stream>>>(fusedbf, wtc, b_ctc, out);
}

// Round 16
// 224.208 us; speedup vs baseline: 1.1447x; 1.0384x over previous
//
#include <hip/hip_runtime.h>
#include <hip/hip_bf16.h>

typedef __bf16 bf16x8 __attribute__((ext_vector_type(8)));
typedef __bf16 bf16x4 __attribute__((ext_vector_type(4)));
typedef float f32x4 __attribute__((ext_vector_type(4)));
typedef float f32x2 __attribute__((ext_vector_type(2)));

__device__ __forceinline__ f32x4 mfma16(bf16x8 a, bf16x8 b, f32x4 c) {
  return __builtin_amdgcn_mfma_f32_16x16x32_bf16(a, b, c, 0, 0, 0);
}

__device__ __forceinline__ bf16x8 cvt8(const float* f) {
  bf16x8 r;
#pragma unroll
  for (int i = 0; i < 8; ++i) r[i] = (__bf16)f[i];
  return r;
}

// Barrier that orders LDS (lgkmcnt) but does NOT drain in-flight vmem
// loads (vmcnt). Safe when the barrier only protects ds_writes and all
// pending global loads target private VGPRs (reg-staged pipelines):
// the compiler still inserts vmcnt waits at each register USE.
#define SYNC_LGKM() \
  asm volatile("s_waitcnt lgkmcnt(0)\n\ts_barrier" ::: "memory")

// ---- block reduction helpers (blockDim.x == 256 assumed, 4 waves) ----
__device__ __forceinline__ void blockRed2(float& a, float& b, float* red) {
#pragma unroll
  for (int off = 1; off < 64; off <<= 1) {
    a += __shfl_xor(a, off, 64);
    b += __shfl_xor(b, off, 64);
  }
  const int w = threadIdx.x >> 6;
  if ((threadIdx.x & 63) == 0) { red[w] = a; red[4 + w] = b; }
  __syncthreads();
  a = red[0] + red[1] + red[2] + red[3];
  b = red[4] + red[5] + red[6] + red[7];
  __syncthreads();
}

// =====================================================================
// Stage A: img_feat partials = images_flat(512x37632) @ W_img(37632x512)
// split-K=49, tile 128x128, BK=32, 8 waves, dbuf LDS, DEPTH-3 register
// pipeline, XCD swizzle, and lgkm-only barriers: hipcc's __syncthreads
// emits s_waitcnt vmcnt(0) which drains the freshest prefetch every
// step (why depth-3 ~= depth-2). Loads here are reg-staged (private),
// so the barrier only needs lgkmcnt for the ds_writes.
// =====================================================================
#define IMG_K 37632
#define SPLITK 49
#define STEPS_PER 24  // divisible by 6 (2-buf x 3-set unroll)

__global__ __launch_bounds__(512) void img_gemm_kernel(
    const float* __restrict__ A, const float* __restrict__ B,
    __bf16* __restrict__ partials) {
  __shared__ __bf16 As[2][128 * 40];
  __shared__ __bf16 Bs[2][128 * 40];
  const int t = threadIdx.x;
  const int lane = t & 63;
  const int w = t >> 6;
  const int wr = (w >> 2) * 64;
  const int wc = (w & 3) * 32;
  const int orig = blockIdx.x + (blockIdx.y << 2) + (blockIdx.z << 4);
  const int swz = (orig & 7) * 98 + (orig >> 3);
  const int m0 = ((swz >> 2) & 3) * 128;
  const int n0 = (swz & 3) * 128;
  const int zz = swz >> 4;
  const int step0 = zz * STEPS_PER;

  f32x4 acc[4][2];
#pragma unroll
  for (int i = 0; i < 4; ++i)
#pragma unroll
    for (int j = 0; j < 2; ++j) acc[i][j] = f32x4{0.f, 0.f, 0.f, 0.f};

  const int ar = t >> 2, ak = (t & 3) * 8;
  const int bn = t & 127, bk = (t >> 7) * 8;
  const int fr = lane & 15, fk = (lane >> 4) * 8;

  float r0a[8], r0b[8], r1a[8], r1b[8], r2a[8], r2b[8];
#define IMG_LOAD(AT, BT, K0)                                                \
  do {                                                                      \
    const float* asrc = A + (size_t)(m0 + ar) * IMG_K + (K0) + ak;          \
    f32x4 v0 = *reinterpret_cast<const f32x4*>(asrc);                       \
    f32x4 v1 = *reinterpret_cast<const f32x4*>(asrc + 4);                   \
    AT[0] = v0[0]; AT[1] = v0[1]; AT[2] = v0[2]; AT[3] = v0[3];             \
    AT[4] = v1[0]; AT[5] = v1[1]; AT[6] = v1[2]; AT[7] = v1[3];             \
    const float* bsrc = B + (size_t)((K0) + bk) * 512 + n0 + bn;            \
    _Pragma("unroll") for (int j = 0; j < 8; ++j) BT[j] =                   \
        bsrc[(size_t)j * 512];                                              \
  } while (0)
#define IMG_WRITE(BUF, AT, BT)                                              \
  do {                                                                      \
    *reinterpret_cast<bf16x8*>(&As[BUF][ar * 40 + ak]) = cvt8(AT);          \
    *reinterpret_cast<bf16x8*>(&Bs[BUF][bn * 40 + bk]) = cvt8(BT);          \
  } while (0)
#define IMG_MFMA(BUF)                                                       \
  do {                                                                      \
    bf16x8 af[4], bfr[2];                                                   \
    _Pragma("unroll") for (int i = 0; i < 4; ++i) af[i] =                   \
        *reinterpret_cast<const bf16x8*>(                                   \
            &As[BUF][(wr + i * 16 + fr) * 40 + fk]);                        \
    _Pragma("unroll") for (int j = 0; j < 2; ++j) bfr[j] =                  \
        *reinterpret_cast<const bf16x8*>(                                   \
            &Bs[BUF][(wc + j * 16 + fr) * 40 + fk]);                        \
    _Pragma("unroll") for (int i = 0; i < 4; ++i)                           \
        _Pragma("unroll") for (int j = 0; j < 2; ++j) acc[i][j] =           \
            mfma16(af[i], bfr[j], acc[i][j]);                               \
  } while (0)
#define IMG_STEP(S, BUF, WBUF, LA, LB, WA, WB)                              \
  do {                                                                      \
    if ((S) + 3 < STEPS_PER) IMG_LOAD(LA, LB, (step0 + (S) + 3) * 32);      \
    IMG_MFMA(BUF);                                                          \
    if ((S) + 1 < STEPS_PER) IMG_WRITE(WBUF, WA, WB);                       \
    SYNC_LGKM();                                                            \
  } while (0)

  IMG_LOAD(r0a, r0b, step0 * 32);
  IMG_WRITE(0, r0a, r0b);
  IMG_LOAD(r1a, r1b, (step0 + 1) * 32);
  IMG_LOAD(r2a, r2b, (step0 + 2) * 32);
  SYNC_LGKM();

  for (int s6 = 0; s6 < STEPS_PER; s6 += 6) {
    IMG_STEP(s6 + 0, 0, 1, r0a, r0b, r1a, r1b);
    IMG_STEP(s6 + 1, 1, 0, r1a, r1b, r2a, r2b);
    IMG_STEP(s6 + 2, 0, 1, r2a, r2b, r0a, r0b);
    IMG_STEP(s6 + 3, 1, 0, r0a, r0b, r1a, r1b);
    IMG_STEP(s6 + 4, 0, 1, r1a, r1b, r2a, r2b);
    IMG_STEP(s6 + 5, 1, 0, r2a, r2b, r0a, r0b);
  }
#undef IMG_LOAD
#undef IMG_WRITE
#undef IMG_MFMA
#undef IMG_STEP

  __bf16* P = partials + (size_t)zz * (512 * 512);
  const int rq = (lane >> 4) * 4;
#pragma unroll
  for (int i = 0; i < 4; ++i)
#pragma unroll
    for (int j = 0; j < 2; ++j)
#pragma unroll
      for (int r = 0; r < 4; ++r)
        P[(size_t)(m0 + wr + i * 16 + rq + r) * 512 + (n0 + wc + j * 16 + fr)] =
            (__bf16)acc[i][j][r];
}

// low[idx] = kp_feat(already there) + b_img + sum_z partials[z][idx];
// also writes bf16 copy into fusedbf. (Scalar 1024-block -- proven;
// 128-block vectorized variant was +12us: keep grid >= CU saturation.)
__global__ __launch_bounds__(256) void reduce_add_kernel(
    const __bf16* __restrict__ partials, const float* __restrict__ b_img,
    float* __restrict__ low, __bf16* __restrict__ fusedbf) {
  const int idx = blockIdx.x * 256 + threadIdx.x;
  float acc = low[idx] + b_img[idx & 511];
#pragma unroll
  for (int z = 0; z < SPLITK; ++z)
    acc += (float)partials[(size_t)z * 262144 + idx];
  low[idx] = acc;
  fusedbf[(size_t)(idx >> 9) * 1024 + (idx & 511)] = (__bf16)acc;
}

// =====================================================================
// prep3: one launch for three same-shape prep passes (1536 blocks)
// =====================================================================
__global__ __launch_bounds__(256) void prep3_kernel(
    const float* __restrict__ W_qp, __bf16* __restrict__ wtq,
    const float* __restrict__ W_kp, __bf16* __restrict__ wkp_t,
    const float* __restrict__ kp, __bf16* __restrict__ kpbf) {
  const int bid = blockIdx.x;
  const int t = threadIdx.x;
  if (bid < 512) {
    wtq[(size_t)bid * 256 + t] =
        (t < 242) ? (__bf16)W_qp[(size_t)t * 512 + bid] : (__bf16)0.f;
  } else if (bid < 1024) {
    const int c = bid - 512;
    wkp_t[(size_t)c * 256 + t] =
        (t < 242) ? (__bf16)W_kp[(size_t)t * 512 + c] : (__bf16)0.f;
  } else {
    const int r = bid - 1024;
    kpbf[(size_t)r * 256 + t] =
        (t < 242) ? (__bf16)kp[(size_t)r * 242 + t] : (__bf16)0.f;
  }
}

// kp projection: kptmp = relu(kpbf @ wkp_t^T + b_kp). Register GEMM.
__global__ __launch_bounds__(256) void kp_gemm_kernel(
    const __bf16* __restrict__ A, const __bf16* __restrict__ Wt,
    const float* __restrict__ bias, float* __restrict__ C) {
  const int t = threadIdx.x, lane = t & 63, w = t >> 6;
  const int n0 = blockIdx.x * 16;
  const int m0 = blockIdx.y * 64 + w * 16;
  const int fr = lane & 15, fq = lane >> 4;
  const __bf16* arow = A + (size_t)(m0 + fr) * 256 + fq * 8;
  const __bf16* brow = Wt + (size_t)(n0 + fr) * 256 + fq * 8;
  f32x4 acc = f32x4{0.f, 0.f, 0.f, 0.f};
#pragma unroll
  for (int ks = 0; ks < 8; ++ks) {
    bf16x8 a = *reinterpret_cast<const bf16x8*>(arow + ks * 32);
    bf16x8 b = *reinterpret_cast<const bf16x8*>(brow + ks * 32);
    acc = mfma16(a, b, acc);
  }
  const int col = n0 + fr;
  const float bv = bias[col];
  const int r0 = m0 + fq * 4;
#pragma unroll
  for (int r = 0; r < 4; ++r)
    C[(size_t)(r0 + r) * 512 + col] = fmaxf(acc[r] + bv, 0.f);
}

// LayerNorm rows of 512 (f32 in -> f32 out into low)
__global__ __launch_bounds__(256) void ln_f32_kernel(
    const float* __restrict__ x, const float* __restrict__ g,
    const float* __restrict__ bt, float* __restrict__ y) {
  __shared__ float red[8];
  const int t = threadIdx.x;
  const size_t off = (size_t)blockIdx.x * 512;
  const float a = x[off + t], b2 = x[off + t + 256];
  float s = a + b2, sq = a * a + b2 * b2;
  blockRed2(s, sq, red);
  const float m = s * (1.f / 512.f);
  const float var = sq * (1.f / 512.f) - m * m;
  const float rs = rsqrtf(var + 1e-5f);
  y[off + t] = (a - m) * rs * g[t] + bt[t];
  y[off + t + 256] = (b2 - m) * rs * g[t + 256] + bt[t + 256];
}

// =====================================================================
// Generic transpose+convert (LDS-tiled): W [NK][NC] f32 -> Wt [NC][NK]
// =====================================================================
__device__ __forceinline__ void wtrans_body(const float* __restrict__ W,
                                            __bf16* __restrict__ Wt, int NC,
                                            int NK, int bx, int by) {
  __shared__ float T[32][33];
  const int t = threadIdx.x;
  const int c0 = bx * 32;
  const int k0 = by * 32;
#pragma unroll
  for (int r = 0; r < 4; ++r) {
    const int idx = r * 256 + t;
    const int i = idx >> 5, j = idx & 31;
    const int c = c0 + j;
    T[i][j] = (c < NC) ? W[(size_t)(k0 + i) * NC + c] : 0.f;
  }
  __syncthreads();
#pragma unroll
  for (int r = 0; r < 4; ++r) {
    const int idx = r * 256 + t;
    const int i = idx >> 5, j = idx & 31;
    const int c = c0 + i;
    if (c < NC) Wt[(size_t)c * NK + k0 + j] = (__bf16)T[j][i];
  }
}

__global__ __launch_bounds__(256) void wtrans_kernel(
    const float* __restrict__ W, __bf16* __restrict__ Wt, int NC, int NK) {
  wtrans_body(W, Wt, NC, NK, blockIdx.x, blockIdx.y);
}

__global__ __launch_bounds__(256) void wtrans4_kernel(
    const float* __restrict__ W0, const float* __restrict__ W1,
    const float* __restrict__ W2, const float* __restrict__ W3,
    __bf16* __restrict__ T0, __bf16* __restrict__ T1,
    __bf16* __restrict__ T2, __bf16* __restrict__ T3) {
  const float* W = (blockIdx.z == 0) ? W0 : (blockIdx.z == 1) ? W1
                   : (blockIdx.z == 2) ? W2 : W3;
  __bf16* Wt = (blockIdx.z == 0) ? T0 : (blockIdx.z == 1) ? T1
               : (blockIdx.z == 2) ? T2 : T3;
  wtrans_body(W, Wt, 512, 512, blockIdx.x, blockIdx.y);
}

// =====================================================================
// Fused MFMA pooling: pooled = pool_mean(LN(qgrids @ W_qp + b_qp)) bf16.
// A-rows LDS-staged per S-iter: all 8 waves share the same 16 rows, so
// stage them coalesced (f32x2) instead of 32x 8B gathers per lane.
// Stride 258 pad -> conflict-free fr reads; cols 242..257 zeroed so the
// k-tail guard disappears (Wt is zero-padded past k=242 too).
// =====================================================================
__global__ __launch_bounds__(512) void pool_mfma_kernel(
    const float* __restrict__ qgrids, const int* __restrict__ lens,
    const __bf16* __restrict__ Wt, const float* __restrict__ bias,
    const float* __restrict__ g, const float* __restrict__ bt,
    __bf16* __restrict__ pooled) {
  __shared__ float red[8][16][2];
  __shared__ float Arows[16][258];
  const int t = threadIdx.x, lane = t & 63, w = t >> 6;
  const int b = blockIdx.x >> 5;
  const int j0 = (blockIdx.x & 31) * 16;
  const int L = lens[b];
  int S = (L + 511) >> 9;
  if (S < 1) S = 1;
  const int new_len = (L + S - 1) / S;
  const float* qg_b = qgrids + (size_t)b * 4096 * 242;
  __bf16* pooled_b = pooled + (size_t)b * 512 * 512;

  const int fr = lane & 15;
  const int fq = lane >> 4;
  const int fkq = fq * 8;
  const int colbase = w * 64;

  float biasv[4], gv[4], btv[4];
#pragma unroll
  for (int nt = 0; nt < 4; ++nt) {
    const int col = colbase + nt * 16 + fr;
    biasv[nt] = bias[col];
    gv[nt] = g[col];
    btv[nt] = bt[col];
  }

  f32x4 pool[4];
#pragma unroll
  for (int nt = 0; nt < 4; ++nt) pool[nt] = f32x4{0.f, 0.f, 0.f, 0.f};

  // zero the pad columns once (they never change)
  {
    const int row = t >> 5, l32 = t & 31;
    if (l32 < 16) Arows[row][242 + l32] = 0.f;
  }

  for (int i = 0; i < S; ++i) {
    // stage the 16 source rows for this window offset (coalesced f32x2)
    {
      const int row = t >> 5, l32 = t & 31;
      const int arow = (j0 + row) * S + i;  // < 4096 always
      const float* src = qg_b + (size_t)arow * 242;
#pragma unroll
      for (int c8 = 0; c8 < 4; ++c8) {
        const int c = (l32 + c8 * 32) * 2;
        if (c < 242) {
          f32x2 v = *reinterpret_cast<const f32x2*>(src + c);
          Arows[row][c] = v[0];
          Arows[row][c + 1] = v[1];
        }
      }
    }
    __syncthreads();
    f32x4 acc[4];
#pragma unroll
    for (int nt = 0; nt < 4; ++nt) acc[nt] = f32x4{0.f, 0.f, 0.f, 0.f};
#pragma unroll
    for (int ks = 0; ks < 8; ++ks) {
      bf16x8 af = cvt8(&Arows[fr][ks * 32 + fkq]);
      const __bf16* wt = Wt + ks * 32 + fkq;
#pragma unroll
      for (int nt = 0; nt < 4; ++nt) {
        bf16x8 bfv = *reinterpret_cast<const bf16x8*>(
            wt + (size_t)(colbase + nt * 16 + fr) * 256);
        acc[nt] = mfma16(af, bfv, acc[nt]);
      }
    }
    float s[4] = {0.f, 0.f, 0.f, 0.f}, sq[4] = {0.f, 0.f, 0.f, 0.f};
#pragma unroll
    for (int nt = 0; nt < 4; ++nt) {
#pragma unroll
      for (int r = 0; r < 4; ++r) {
        const float v = acc[nt][r] + biasv[nt];
        acc[nt][r] = v;
        s[r] += v;
        sq[r] += v * v;
      }
    }
#pragma unroll
    for (int off = 1; off < 16; off <<= 1) {
#pragma unroll
      for (int r = 0; r < 4; ++r) {
        s[r] += __shfl_xor(s[r], off, 64);
        sq[r] += __shfl_xor(sq[r], off, 64);
      }
    }
    if (fr == 0) {
#pragma unroll
      for (int r = 0; r < 4; ++r) {
        red[w][fq * 4 + r][0] = s[r];
        red[w][fq * 4 + r][1] = sq[r];
      }
    }
    __syncthreads();
    float mean[4], rsig[4];
#pragma unroll
    for (int r = 0; r < 4; ++r) {
      const int p = fq * 4 + r;
      float ss = 0.f, qq = 0.f;
#pragma unroll
      for (int ww = 0; ww < 8; ++ww) {
        ss += red[ww][p][0];
        qq += red[ww][p][1];
      }
      const float m = ss * (1.f / 512.f);
      mean[r] = m;
      rsig[r] = rsqrtf(qq * (1.f / 512.f) - m * m + 1e-5f);
    }
    __syncthreads();
#pragma unroll
    for (int r = 0; r < 4; ++r) {
      const int srow = (j0 + fq * 4 + r) * S + i;
      const bool ok = srow < L;
#pragma unroll
      for (int nt = 0; nt < 4; ++nt) {
        const float nv = (acc[nt][r] - mean[r]) * rsig[r] * gv[nt] + btv[nt];
        pool[nt][r] += ok ? nv : 0.f;
      }
    }
  }
  const float inv = 1.f / (float)S;
#pragma unroll
  for (int r = 0; r < 4; ++r) {
    const int j = j0 + fq * 4 + r;
    const bool ok = j < new_len;
#pragma unroll
    for (int nt = 0; nt < 4; ++nt)
      pooled_b[(size_t)j * 512 + colbase + nt * 16 + fr] =
          (__bf16)(ok ? pool[nt][r] * inv : 0.f);
  }
}

// =====================================================================
// Register GEMM, K=512: one 16x16 tile per wave, no LDS, no barriers.
// =====================================================================
template <typename OutT>
__global__ __launch_bounds__(256) void reg_gemm512_kernel(
    const __bf16* __restrict__ A, int lda, const __bf16* __restrict__ Wt,
    const float* __restrict__ bias, OutT* __restrict__ C, int ldc) {
  const int t = threadIdx.x, lane = t & 63, w = t >> 6;
  const int n0 = blockIdx.x * 16;
  const int m0 = blockIdx.y * 64 + w * 16;
  const int fr = lane & 15, fq = lane >> 4;
  const __bf16* arow = A + (size_t)(m0 + fr) * lda + fq * 8;
  const __bf16* brow = Wt + (size_t)(n0 + fr) * 512 + fq * 8;
  f32x4 acc = f32x4{0.f, 0.f, 0.f, 0.f};
#pragma unroll
  for (int ks = 0; ks < 16; ++ks) {
    bf16x8 a = *reinterpret_cast<const bf16x8*>(arow + ks * 32);
    bf16x8 b = *reinterpret_cast<const bf16x8*>(brow + ks * 32);
    acc = mfma16(a, b, acc);
  }
  const int col = n0 + fr;
  const float bv = bias[col];
  const int r0 = m0 + fq * 4;
#pragma unroll
  for (int r = 0; r < 4; ++r)
    C[(size_t)(r0 + r) * ldc + col] = (OutT)(acc[r] + bv);
}

// K+V in one launch (blockIdx.z picks weight/bias/output)
__global__ __launch_bounds__(256) void kv_reg_gemm_kernel(
    const __bf16* __restrict__ A, const __bf16* __restrict__ wk_t,
    const float* __restrict__ bk, const __bf16* __restrict__ wv_t,
    const float* __restrict__ bv, __bf16* __restrict__ kout,
    __bf16* __restrict__ vout) {
  const __bf16* Wt = blockIdx.z ? wv_t : wk_t;
  const float* bias = blockIdx.z ? bv : bk;
  __bf16* C = blockIdx.z ? vout : kout;
  const int t = threadIdx.x, lane = t & 63, w = t >> 6;
  const int n0 = blockIdx.x * 16;
  const int m0 = blockIdx.y * 64 + w * 16;
  const int fr = lane & 15, fq = lane >> 4;
  const __bf16* arow = A + (size_t)(m0 + fr) * 512 + fq * 8;
  const __bf16* brow = Wt + (size_t)(n0 + fr) * 512 + fq * 8;
  f32x4 acc = f32x4{0.f, 0.f, 0.f, 0.f};
#pragma unroll
  for (int ks = 0; ks < 16; ++ks) {
    bf16x8 a = *reinterpret_cast<const bf16x8*>(arow + ks * 32);
    bf16x8 b = *reinterpret_cast<const bf16x8*>(brow + ks * 32);
    acc = mfma16(a, b, acc);
  }
  const int col = n0 + fr;
  const float bvv = bias[col];
  const int r0 = m0 + fq * 4;
#pragma unroll
  for (int r = 0; r < 4; ++r)
    C[(size_t)(r0 + r) * 512 + col] = (__bf16)(acc[r] + bvv);
}

// =====================================================================
// CTC head register GEMM: out[512,1296] = fusedbf @ Wt^T + bias (K=1024)
// =====================================================================
__global__ __launch_bounds__(256) void ctc_gemm_kernel(
    const __bf16* __restrict__ A, const __bf16* __restrict__ Wt,
    const float* __restrict__ bias, float* __restrict__ out) {
  const int t = threadIdx.x, lane = t & 63, w = t >> 6;
  const int n0 = blockIdx.x * 16;
  const int m0 = blockIdx.y * 64 + w * 16;
  const int fr = lane & 15, fq = lane >> 4;
  const __bf16* arow = A + (size_t)(m0 + fr) * 1024 + fq * 8;
  const __bf16* brow = Wt + (size_t)(n0 + fr) * 1024 + fq * 8;
  f32x4 acc = f32x4{0.f, 0.f, 0.f, 0.f};
#pragma unroll
  for (int ks = 0; ks < 32; ++ks) {
    bf16x8 a = *reinterpret_cast<const bf16x8*>(arow + ks * 32);
    bf16x8 b = *reinterpret_cast<const bf16x8*>(brow + ks * 32);
    acc = mfma16(a, b, acc);
  }
  const int col = n0 + fr;
  const float bv = bias[col];
  const int r0 = m0 + fq * 4;
#pragma unroll
  for (int r = 0; r < 4; ++r)
    out[(size_t)(r0 + r) * 1296 + col] = acc[r] + bv;
}

// =====================================================================
// Fused attention: one block per (b,h). scores -> softmax -> P in LDS
// -> stage all of V (XOR-swizzled k) -> 16 barrier-free PV sub-steps.
// =====================================================================
__global__ __launch_bounds__(256) void attn_fused_kernel(
    const __bf16* __restrict__ q, const __bf16* __restrict__ k,
    const __bf16* __restrict__ v, const int* __restrict__ lens,
    __bf16* __restrict__ ctx) {
  __shared__ __bf16 Qs[64 * 72];
  __shared__ __bf16 Ps[64 * 520];
  __shared__ __bf16 KVs[64 * 520];
  const int t = threadIdx.x, lane = t & 63, w = t >> 6;
  const int bh = blockIdx.x, b = bh >> 3, h = bh & 7;
  const int L = lens[b];
  const int sdiv = (L + 511) >> 9;
  const int new_len = (L + sdiv - 1) / sdiv;
  const size_t qbase = (size_t)b * 64 * 512 + h * 64;
  const size_t kbase = (size_t)b * 512 * 512 + h * 64;
  const size_t vbase = kbase;
  const int fr = lane & 15, fkq = (lane >> 4) * 8;

#pragma unroll
  for (int rep = 0; rep < 4; ++rep) {
    const int gidx = rep * 256 + t;
    const int row = gidx >> 4, c = (gidx & 15) * 4;
    *reinterpret_cast<bf16x4*>(&Qs[row * 72 + c]) =
        *reinterpret_cast<const bf16x4*>(&q[qbase + (size_t)row * 512 + c]);
  }
  f32x4 acc[32];
#pragma unroll
  for (int nt = 0; nt < 32; ++nt) acc[nt] = f32x4{0.f, 0.f, 0.f, 0.f};
  for (int ks = 0; ks < 2; ++ks) {
    const int k0 = ks * 32;
#pragma unroll
    for (int rep = 0; rep < 16; ++rep) {
      const int gidx = rep * 256 + t;
      const int row = gidx >> 3, c = (gidx & 7) * 4;
      *reinterpret_cast<bf16x4*>(&KVs[row * 40 + c]) =
          *reinterpret_cast<const bf16x4*>(&k[kbase + (size_t)row * 512 + k0 + c]);
    }
    __syncthreads();
    const bf16x8 af =
        *reinterpret_cast<const bf16x8*>(&Qs[(w * 16 + fr) * 72 + k0 + fkq]);
#pragma unroll
    for (int nt = 0; nt < 32; ++nt) {
      bf16x8 bf = *reinterpret_cast<const bf16x8*>(&KVs[(nt * 16 + fr) * 40 + fkq]);
      acc[nt] = mfma16(af, bf, acc[nt]);
    }
    __syncthreads();
  }
  const float scale = 0.125f;
#pragma unroll
  for (int r = 0; r < 4; ++r) {
    float mx = -3.0e38f;
#pragma unroll
    for (int nt = 0; nt < 32; ++nt) {
      const int col = nt * 16 + fr;
      const float sv = acc[nt][r] * scale;
      if (col < new_len) mx = fmaxf(mx, sv);
    }
#pragma unroll
    for (int off = 1; off < 16; off <<= 1) mx = fmaxf(mx, __shfl_xor(mx, off, 64));
    float sum = 0.f;
#pragma unroll
    for (int nt = 0; nt < 32; ++nt) {
      const int col = nt * 16 + fr;
      const float e = (col < new_len) ? __expf(acc[nt][r] * scale - mx) : 0.f;
      acc[nt][r] = e;
      sum += e;
    }
#pragma unroll
    for (int off = 1; off < 16; off <<= 1) sum += __shfl_xor(sum, off, 64);
    const float inv = 1.f / sum;
    const int row = w * 16 + ((lane >> 4) << 2) + r;
#pragma unroll
    for (int nt = 0; nt < 32; ++nt)
      Ps[row * 520 + nt * 16 + fr] = (__bf16)(acc[nt][r] * inv);
  }
  __syncthreads();
  {
    const int d = t & 63;
    const int kc = (t >> 6) * 128;
    const int sw = (d & 7) << 3;
#pragma unroll
    for (int j8 = 0; j8 < 16; ++j8) {
      const int kv0 = kc + j8 * 8;
      bf16x8 tmp;
#pragma unroll
      for (int jj = 0; jj < 8; ++jj)
        tmp[jj] = v[vbase + (size_t)(kv0 + jj) * 512 + d];
      *reinterpret_cast<bf16x8*>(&KVs[d * 520 + (kv0 ^ sw)]) = tmp;
    }
  }
  __syncthreads();
  f32x4 acc2[4];
#pragma unroll
  for (int nt = 0; nt < 4; ++nt) acc2[nt] = f32x4{0.f, 0.f, 0.f, 0.f};
  const int swr = (fr & 7) << 3;
#pragma unroll
  for (int s = 0; s < 16; ++s) {
    const int k0 = s * 32;
    const bf16x8 af =
        *reinterpret_cast<const bf16x8*>(&Ps[(w * 16 + fr) * 520 + k0 + fkq]);
#pragma unroll
    for (int nt = 0; nt < 4; ++nt) {
      bf16x8 bf = *reinterpret_cast<const bf16x8*>(
          &KVs[(nt * 16 + fr) * 520 + ((k0 + fkq) ^ swr)]);
      acc2[nt] = mfma16(af, bf, acc2[nt]);
    }
  }
  const int rq = (lane >> 4) * 4;
  const size_t cbase = (size_t)b * 64 * 512 + h * 64;
#pragma unroll
  for (int nt = 0; nt < 4; ++nt)
#pragma unroll
    for (int r = 0; r < 4; ++r)
      ctx[cbase + (size_t)(w * 16 + rq + r) * 512 + nt * 16 + fr] =
          (__bf16)acc2[nt][r];
}

// LayerNorm over rows of 512, bf16 output into fusedbf[:, 512:1024]
__global__ __launch_bounds__(256) void ln_bf16_kernel(
    const float* __restrict__ x, const float* __restrict__ g,
    const float* __restrict__ bt, __bf16* __restrict__ ybf) {
  __shared__ float red[8];
  const int t = threadIdx.x;
  const size_t off = (size_t)blockIdx.x * 512;
  const float a = x[off + t], b2 = x[off + t + 256];
  float s = a + b2, sq = a * a + b2 * b2;
  blockRed2(s, sq, red);
  const float m = s * (1.f / 512.f);
  const float var = sq * (1.f / 512.f) - m * m;
  const float rs = rsqrtf(var + 1e-5f);
  __bf16* yrow = ybf + (size_t)blockIdx.x * 1024;
  yrow[t] = (__bf16)((a - m) * rs * g[t] + bt[t]);
  yrow[t + 256] = (__bf16)((b2 - m) * rs * g[t + 256] + bt[t + 256]);
}

// =====================================================================
// Workspace layout identical to round 15 (proven).
// =====================================================================
extern "C" void kernel_launch(void* const* d_in, const int* in_sizes, int n_in,
                              void* d_out, int out_size, void* d_ws,
                              size_t ws_size, hipStream_t stream) {
  const float* images = (const float*)d_in[0];
  const float* qgrids = (const float*)d_in[1];
  const float* keypoints = (const float*)d_in[2];
  const int* qlens = (const int*)d_in[3];
  const float* W_img = (const float*)d_in[4];
  const float* b_img = (const float*)d_in[5];
  const float* W_kp = (const float*)d_in[6];
  const float* b_kp = (const float*)d_in[7];
  const float* g_kp = (const float*)d_in[8];
  const float* bt_kp = (const float*)d_in[9];
  const float* W_qp = (const float*)d_in[10];
  const float* b_qp = (const float*)d_in[11];
  const float* g_qln = (const float*)d_in[12];
  const float* bt_qln = (const float*)d_in[13];
  const float* Wq = (const float*)d_in[14];
  const float* bq = (const float*)d_in[15];
  const float* Wk = (const float*)d_in[16];
  const float* bk = (const float*)d_in[17];
  const float* Wv = (const float*)d_in[18];
  const float* bv = (const float*)d_in[19];
  const float* Wo = (const float*)d_in[20];
  const float* bo = (const float*)d_in[21];
  const float* g_attn = (const float*)d_in[22];
  const float* bt_attn = (const float*)d_in[23];
  const float* W_ctc = (const float*)d_in[24];
  const float* b_ctc = (const float*)d_in[25];
  float* out = (float*)d_out;

  const size_t MB = 1u << 20;
  const size_t KB = 1u << 10;
  if (ws_size < 35 * MB + 512 * KB) return;
  char* ws = (char*)d_ws;
  float* low = (float*)(ws);
  __bf16* qbuf = (__bf16*)(ws + 1 * MB);
  __bf16* wtq = (__bf16*)(ws + 2 * MB);
  float* ctxo = (float*)(ws + 2 * MB);
  __bf16* fusedbf = (__bf16*)(ws + 3 * MB);
  __bf16* partials = (__bf16*)(ws + 4 * MB);
  __bf16* pooled = (__bf16*)(ws + 4 * MB);
  __bf16* kbuf = (__bf16*)(ws + 12 * MB);
  __bf16* vbuf = (__bf16*)(ws + 16 * MB);
  __bf16* ctxbf = (__bf16*)(ws + 28 * MB);
  __bf16* wtc = (__bf16*)(ws + 29 * MB);
  __bf16* wq_t = (__bf16*)(ws + 32 * MB);
  __bf16* wk_t = (__bf16*)(ws + 32 * MB + 512 * KB);
  __bf16* wv_t = (__bf16*)(ws + 33 * MB);
  __bf16* wo_t = (__bf16*)(ws + 33 * MB + 512 * KB);
  __bf16* kpbf = (__bf16*)(ws + 34 * MB);
  __bf16* wkp_t = (__bf16*)(ws + 34 * MB + 256 * KB);
  float* kptmp = (float*)(ws + 34 * MB + 512 * KB);

  // 0) prep: wqp^T + wkp^T + kp cast (one launch), qkvo transposes, ctc^T
  prep3_kernel<<<1536, 256, 0, stream>>>(W_qp, wtq, W_kp, wkp_t, keypoints,
                                         kpbf);
  wtrans4_kernel<<<dim3(16, 16, 4), 256, 0, stream>>>(Wq, Wk, Wv, Wo, wq_t,
                                                      wk_t, wv_t, wo_t);
  wtrans_kernel<<<dim3(41, 32), 256, 0, stream>>>(W_ctc, wtc, 1296, 1024);
  // 1) img GEMM partials (split-K=49, BK=32, depth-3, lgkm-only barriers)
  img_gemm_kernel<<<dim3(4, 4, SPLITK), 512, 0, stream>>>(images, W_img, partials);
  // 2) kp proj via register GEMM (+relu), then LN -> low
  kp_gemm_kernel<<<dim3(32, 8), 256, 0, stream>>>(kpbf, wkp_t, b_kp, kptmp);
  ln_f32_kernel<<<512, 256, 0, stream>>>(kptmp, g_kp, bt_kp, low);
  // 3) low += b_img + sum(partials); fusedbf[:, :512] = bf16(low)
  reduce_add_kernel<<<1024, 256, 0, stream>>>(partials, b_img, low, fusedbf);
  // 4) pooled qgrid tokens -> bf16 (A rows LDS-staged)
  pool_mfma_kernel<<<256, 512, 0, stream>>>(qgrids, qlens, wtq, b_qp, g_qln,
                                            bt_qln, pooled);
  // 5) k + v via register GEMM, one launch
  kv_reg_gemm_kernel<<<dim3(32, 64, 2), 256, 0, stream>>>(pooled, wk_t, bk,
                                                          wv_t, bv, kbuf, vbuf);
  // 6) q via register GEMM (A = fusedbf low-half, lda=1024)
  reg_gemm512_kernel<__bf16><<<dim3(32, 8), 256, 0, stream>>>(
      fusedbf, 1024, wq_t, bq, qbuf, 512);
  // 7) fused attention (scores+softmax+PV, P in LDS)
  attn_fused_kernel<<<64, 256, 0, stream>>>(qbuf, kbuf, vbuf, qlens, ctxbf);
  // 8) ctx @ Wo + bo (f32 out), then LN -> fusedbf[:, 512:]
  reg_gemm512_kernel<float><<<dim3(32, 8), 256, 0, stream>>>(
      ctxbf, 512, wo_t, bo, ctxo, 512);
  ln_bf16_kernel<<<512, 256, 0, stream>>>(ctxo, g_attn, bt_attn, fusedbf + 512);
  // 9) out = fusedbf @ Wt_ctc^T + b_ctc
  ctc_gemm_kernel<<<dim3(81, 8), 256, 0, stream>>>(fusedbf, wtc, b_ctc, out);
}

// Round 17
// 204.166 us; speedup vs baseline: 1.2571x; 1.0982x over previous
//
#include <hip/hip_runtime.h>
#include <hip/hip_bf16.h>

typedef __bf16 bf16x8 __attribute__((ext_vector_type(8)));
typedef __bf16 bf16x4 __attribute__((ext_vector_type(4)));
typedef float f32x4 __attribute__((ext_vector_type(4)));
typedef float f32x2 __attribute__((ext_vector_type(2)));

__device__ __forceinline__ f32x4 mfma16(bf16x8 a, bf16x8 b, f32x4 c) {
  return __builtin_amdgcn_mfma_f32_16x16x32_bf16(a, b, c, 0, 0, 0);
}

__device__ __forceinline__ bf16x8 cvt8(const float* f) {
  bf16x8 r;
#pragma unroll
  for (int i = 0; i < 8; ++i) r[i] = (__bf16)f[i];
  return r;
}

// lgkm-only barrier (proven numerically safe in round 16)
#define SYNC_LGKM() \
  asm volatile("s_waitcnt lgkmcnt(0)\n\ts_barrier" ::: "memory")

// ---- block reduction helper (blockDim.x == 256, 4 waves) ----
__device__ __forceinline__ void blockRed2(float& a, float& b, float* red) {
#pragma unroll
  for (int off = 1; off < 64; off <<= 1) {
    a += __shfl_xor(a, off, 64);
    b += __shfl_xor(b, off, 64);
  }
  const int w = threadIdx.x >> 6;
  if ((threadIdx.x & 63) == 0) { red[w] = a; red[4 + w] = b; }
  __syncthreads();
  a = red[0] + red[1] + red[2] + red[3];
  b = red[4] + red[5] + red[6] + red[7];
  __syncthreads();
}

#define IMG_K 37632
#define SPLITK 49
#define STEPS_PER 24

// =====================================================================
// img body: split-K=49, 128x128 tile, BK=32, depth-3 reg pipeline,
// XCD swizzle, lgkm-only barriers. (Proven 83us config, unchanged.)
// =====================================================================
__device__ __forceinline__ void img_body(
    int orig, const float* __restrict__ A, const float* __restrict__ B,
    __bf16* __restrict__ partials, __bf16 (*As)[5120], __bf16 (*Bs)[5120]) {
  const int t = threadIdx.x;
  const int lane = t & 63;
  const int w = t >> 6;
  const int wr = (w >> 2) * 64;
  const int wc = (w & 3) * 32;
  const int swz = (orig & 7) * 98 + (orig >> 3);
  const int m0 = ((swz >> 2) & 3) * 128;
  const int n0 = (swz & 3) * 128;
  const int zz = swz >> 4;
  const int step0 = zz * STEPS_PER;

  f32x4 acc[4][2];
#pragma unroll
  for (int i = 0; i < 4; ++i)
#pragma unroll
    for (int j = 0; j < 2; ++j) acc[i][j] = f32x4{0.f, 0.f, 0.f, 0.f};

  const int ar = t >> 2, ak = (t & 3) * 8;
  const int bn = t & 127, bk = (t >> 7) * 8;
  const int fr = lane & 15, fk = (lane >> 4) * 8;

  float r0a[8], r0b[8], r1a[8], r1b[8], r2a[8], r2b[8];
#define IMG_LOAD(AT, BT, K0)                                                \
  do {                                                                      \
    const float* asrc = A + (size_t)(m0 + ar) * IMG_K + (K0) + ak;          \
    f32x4 v0 = *reinterpret_cast<const f32x4*>(asrc);                       \
    f32x4 v1 = *reinterpret_cast<const f32x4*>(asrc + 4);                   \
    AT[0] = v0[0]; AT[1] = v0[1]; AT[2] = v0[2]; AT[3] = v0[3];             \
    AT[4] = v1[0]; AT[5] = v1[1]; AT[6] = v1[2]; AT[7] = v1[3];             \
    const float* bsrc = B + (size_t)((K0) + bk) * 512 + n0 + bn;            \
    _Pragma("unroll") for (int j = 0; j < 8; ++j) BT[j] =                   \
        bsrc[(size_t)j * 512];                                              \
  } while (0)
#define IMG_WRITE(BUF, AT, BT)                                              \
  do {                                                                      \
    *reinterpret_cast<bf16x8*>(&As[BUF][ar * 40 + ak]) = cvt8(AT);          \
    *reinterpret_cast<bf16x8*>(&Bs[BUF][bn * 40 + bk]) = cvt8(BT);          \
  } while (0)
#define IMG_MFMA(BUF)                                                       \
  do {                                                                      \
    bf16x8 af[4], bfr[2];                                                   \
    _Pragma("unroll") for (int i = 0; i < 4; ++i) af[i] =                   \
        *reinterpret_cast<const bf16x8*>(                                   \
            &As[BUF][(wr + i * 16 + fr) * 40 + fk]);                        \
    _Pragma("unroll") for (int j = 0; j < 2; ++j) bfr[j] =                  \
        *reinterpret_cast<const bf16x8*>(                                   \
            &Bs[BUF][(wc + j * 16 + fr) * 40 + fk]);                        \
    _Pragma("unroll") for (int i = 0; i < 4; ++i)                           \
        _Pragma("unroll") for (int j = 0; j < 2; ++j) acc[i][j] =           \
            mfma16(af[i], bfr[j], acc[i][j]);                               \
  } while (0)
#define IMG_STEP(S, BUF, WBUF, LA, LB, WA, WB)                              \
  do {                                                                      \
    if ((S) + 3 < STEPS_PER) IMG_LOAD(LA, LB, (step0 + (S) + 3) * 32);      \
    IMG_MFMA(BUF);                                                          \
    if ((S) + 1 < STEPS_PER) IMG_WRITE(WBUF, WA, WB);                       \
    SYNC_LGKM();                                                            \
  } while (0)

  IMG_LOAD(r0a, r0b, step0 * 32);
  IMG_WRITE(0, r0a, r0b);
  IMG_LOAD(r1a, r1b, (step0 + 1) * 32);
  IMG_LOAD(r2a, r2b, (step0 + 2) * 32);
  SYNC_LGKM();

  for (int s6 = 0; s6 < STEPS_PER; s6 += 6) {
    IMG_STEP(s6 + 0, 0, 1, r0a, r0b, r1a, r1b);
    IMG_STEP(s6 + 1, 1, 0, r1a, r1b, r2a, r2b);
    IMG_STEP(s6 + 2, 0, 1, r2a, r2b, r0a, r0b);
    IMG_STEP(s6 + 3, 1, 0, r0a, r0b, r1a, r1b);
    IMG_STEP(s6 + 4, 0, 1, r1a, r1b, r2a, r2b);
    IMG_STEP(s6 + 5, 1, 0, r2a, r2b, r0a, r0b);
  }
#undef IMG_LOAD
#undef IMG_WRITE
#undef IMG_MFMA
#undef IMG_STEP

  __bf16* P = partials + (size_t)zz * (512 * 512);
  const int rq = (lane >> 4) * 4;
#pragma unroll
  for (int i = 0; i < 4; ++i)
#pragma unroll
    for (int j = 0; j < 2; ++j)
#pragma unroll
      for (int r = 0; r < 4; ++r)
        P[(size_t)(m0 + wr + i * 16 + rq + r) * 512 + (n0 + wc + j * 16 + fr)] =
            (__bf16)acc[i][j][r];
}

// =====================================================================
// pool body: pool_mean(LN(qgrids @ W_qp + b_qp)) -> bf16, A-rows staged
// in LDS (round-16 proven). 512 threads, block-uniform.
// =====================================================================
__device__ __forceinline__ void pool_body(
    int pbid, const float* __restrict__ qgrids, const int* __restrict__ lens,
    const __bf16* __restrict__ Wt, const float* __restrict__ bias,
    const float* __restrict__ g, const float* __restrict__ bt,
    __bf16* __restrict__ pooled, float (*red)[16][2], float (*Arows)[258]) {
  const int t = threadIdx.x, lane = t & 63, w = t >> 6;
  const int b = pbid >> 5;
  const int j0 = (pbid & 31) * 16;
  const int L = lens[b];
  int S = (L + 511) >> 9;
  if (S < 1) S = 1;
  const int new_len = (L + S - 1) / S;
  const float* qg_b = qgrids + (size_t)b * 4096 * 242;
  __bf16* pooled_b = pooled + (size_t)b * 512 * 512;

  const int fr = lane & 15;
  const int fq = lane >> 4;
  const int fkq = fq * 8;
  const int colbase = w * 64;

  float biasv[4], gv[4], btv[4];
#pragma unroll
  for (int nt = 0; nt < 4; ++nt) {
    const int col = colbase + nt * 16 + fr;
    biasv[nt] = bias[col];
    gv[nt] = g[col];
    btv[nt] = bt[col];
  }

  f32x4 pool[4];
#pragma unroll
  for (int nt = 0; nt < 4; ++nt) pool[nt] = f32x4{0.f, 0.f, 0.f, 0.f};

  {
    const int row = t >> 5, l32 = t & 31;
    if (l32 < 16) Arows[row][242 + l32] = 0.f;
  }

  for (int i = 0; i < S; ++i) {
    {
      const int row = t >> 5, l32 = t & 31;
      const int arow = (j0 + row) * S + i;
      const float* src = qg_b + (size_t)arow * 242;
#pragma unroll
      for (int c8 = 0; c8 < 4; ++c8) {
        const int c = (l32 + c8 * 32) * 2;
        if (c < 242) {
          f32x2 v = *reinterpret_cast<const f32x2*>(src + c);
          Arows[row][c] = v[0];
          Arows[row][c + 1] = v[1];
        }
      }
    }
    __syncthreads();
    f32x4 acc[4];
#pragma unroll
    for (int nt = 0; nt < 4; ++nt) acc[nt] = f32x4{0.f, 0.f, 0.f, 0.f};
#pragma unroll
    for (int ks = 0; ks < 8; ++ks) {
      bf16x8 af = cvt8(&Arows[fr][ks * 32 + fkq]);
      const __bf16* wt = Wt + ks * 32 + fkq;
#pragma unroll
      for (int nt = 0; nt < 4; ++nt) {
        bf16x8 bfv = *reinterpret_cast<const bf16x8*>(
            wt + (size_t)(colbase + nt * 16 + fr) * 256);
        acc[nt] = mfma16(af, bfv, acc[nt]);
      }
    }
    float s[4] = {0.f, 0.f, 0.f, 0.f}, sq[4] = {0.f, 0.f, 0.f, 0.f};
#pragma unroll
    for (int nt = 0; nt < 4; ++nt) {
#pragma unroll
      for (int r = 0; r < 4; ++r) {
        const float v = acc[nt][r] + biasv[nt];
        acc[nt][r] = v;
        s[r] += v;
        sq[r] += v * v;
      }
    }
#pragma unroll
    for (int off = 1; off < 16; off <<= 1) {
#pragma unroll
      for (int r = 0; r < 4; ++r) {
        s[r] += __shfl_xor(s[r], off, 64);
        sq[r] += __shfl_xor(sq[r], off, 64);
      }
    }
    if (fr == 0) {
#pragma unroll
      for (int r = 0; r < 4; ++r) {
        red[w][fq * 4 + r][0] = s[r];
        red[w][fq * 4 + r][1] = sq[r];
      }
    }
    __syncthreads();
    float mean[4], rsig[4];
#pragma unroll
    for (int r = 0; r < 4; ++r) {
      const int p = fq * 4 + r;
      float ss = 0.f, qq = 0.f;
#pragma unroll
      for (int ww = 0; ww < 8; ++ww) {
        ss += red[ww][p][0];
        qq += red[ww][p][1];
      }
      const float m = ss * (1.f / 512.f);
      mean[r] = m;
      rsig[r] = rsqrtf(qq * (1.f / 512.f) - m * m + 1e-5f);
    }
    __syncthreads();
#pragma unroll
    for (int r = 0; r < 4; ++r) {
      const int srow = (j0 + fq * 4 + r) * S + i;
      const bool ok = srow < L;
#pragma unroll
      for (int nt = 0; nt < 4; ++nt) {
        const float nv = (acc[nt][r] - mean[r]) * rsig[r] * gv[nt] + btv[nt];
        pool[nt][r] += ok ? nv : 0.f;
      }
    }
  }
  const float inv = 1.f / (float)S;
#pragma unroll
  for (int r = 0; r < 4; ++r) {
    const int j = j0 + fq * 4 + r;
    const bool ok = j < new_len;
#pragma unroll
    for (int nt = 0; nt < 4; ++nt)
      pooled_b[(size_t)j * 512 + colbase + nt * 16 + fr] =
          (__bf16)(ok ? pool[nt][r] * inv : 0.f);
  }
}

// kp body (512-thread mapping): kptmp = relu(kpbf @ wkp_t^T + b_kp).
// kpbid in [0,128): n0 = (kpbid&31)*16, m0 = (kpbid>>5)*128 + wave*16.
__device__ __forceinline__ void kp_body(
    int kpbid, const __bf16* __restrict__ A, const __bf16* __restrict__ Wt,
    const float* __restrict__ bias, float* __restrict__ C) {
  const int t = threadIdx.x, lane = t & 63, w = t >> 6;
  const int n0 = (kpbid & 31) * 16;
  const int m0 = (kpbid >> 5) * 128 + w * 16;
  const int fr = lane & 15, fq = lane >> 4;
  const __bf16* arow = A + (size_t)(m0 + fr) * 256 + fq * 8;
  const __bf16* brow = Wt + (size_t)(n0 + fr) * 256 + fq * 8;
  f32x4 acc = f32x4{0.f, 0.f, 0.f, 0.f};
#pragma unroll
  for (int ks = 0; ks < 8; ++ks) {
    bf16x8 a = *reinterpret_cast<const bf16x8*>(arow + ks * 32);
    bf16x8 b = *reinterpret_cast<const bf16x8*>(brow + ks * 32);
    acc = mfma16(a, b, acc);
  }
  const int col = n0 + fr;
  const float bv = bias[col];
  const int r0 = m0 + fq * 4;
#pragma unroll
  for (int r = 0; r < 4; ++r)
    C[(size_t)(r0 + r) * 512 + col] = fmaxf(acc[r] + bv, 0.f);
}

// =====================================================================
// Phase-1 fused launch: pool (bid<256) | img (bid<1040) | kp (else).
// pool/kp are independent of img -> they fill img's latency stalls.
// LDS: union of img (40960B) and pool (17536B).
// =====================================================================
__global__ __launch_bounds__(512) void phase1_kernel(
    const float* __restrict__ images, const float* __restrict__ W_img,
    __bf16* __restrict__ partials, const float* __restrict__ qgrids,
    const int* __restrict__ lens, const __bf16* __restrict__ wtq,
    const float* __restrict__ b_qp, const float* __restrict__ g_qln,
    const float* __restrict__ bt_qln, __bf16* __restrict__ pooled,
    const __bf16* __restrict__ kpbf, const __bf16* __restrict__ wkp_t,
    const float* __restrict__ b_kp, float* __restrict__ kptmp) {
  __shared__ union {
    struct {
      __bf16 As[2][5120];
      __bf16 Bs[2][5120];
    } img;
    struct {
      float red[8][16][2];
      float Arows[16][258];
    } pool;
  } sm;
  const int bid = blockIdx.x;
  if (bid < 256) {
    pool_body(bid, qgrids, lens, wtq, b_qp, g_qln, bt_qln, pooled,
              sm.pool.red, sm.pool.Arows);
  } else if (bid < 1040) {
    img_body(bid - 256, images, W_img, partials, sm.img.As, sm.img.Bs);
  } else {
    kp_body(bid - 1040, kpbf, wkp_t, b_kp, kptmp);
  }
}

// =====================================================================
// reduce_ln: fusedbf[row, :512] = bf16( LN(kptmp[row])*g+bt + b_img
//                                       + sum_z partials[z][row] ).
// One block per row (512 blocks); f32 'low' array eliminated (dead).
// =====================================================================
__global__ __launch_bounds__(256) void reduce_ln_kernel(
    const float* __restrict__ kptmp, const float* __restrict__ g,
    const float* __restrict__ bt, const __bf16* __restrict__ partials,
    const float* __restrict__ b_img, __bf16* __restrict__ fusedbf) {
  __shared__ float red[8];
  const int t = threadIdx.x;
  const int row = blockIdx.x;
  const size_t off = (size_t)row * 512;
  const float a = kptmp[off + t], b2 = kptmp[off + t + 256];
  float s = a + b2, sq = a * a + b2 * b2;
  blockRed2(s, sq, red);
  const float m = s * (1.f / 512.f);
  const float var = sq * (1.f / 512.f) - m * m;
  const float rs = rsqrtf(var + 1e-5f);
  float acc0 = (a - m) * rs * g[t] + bt[t] + b_img[t];
  float acc1 = (b2 - m) * rs * g[t + 256] + bt[t + 256] + b_img[t + 256];
#pragma unroll
  for (int z = 0; z < SPLITK; ++z) {
    acc0 += (float)partials[(size_t)z * 262144 + off + t];
    acc1 += (float)partials[(size_t)z * 262144 + off + t + 256];
  }
  __bf16* dst = fusedbf + (size_t)row * 1024;
  dst[t] = (__bf16)acc0;
  dst[t + 256] = (__bf16)acc1;
}

// =====================================================================
// prep3: wqp^T | wkp^T | kp cast (1536 blocks, 256 thr)
// =====================================================================
__global__ __launch_bounds__(256) void prep3_kernel(
    const float* __restrict__ W_qp, __bf16* __restrict__ wtq,
    const float* __restrict__ W_kp, __bf16* __restrict__ wkp_t,
    const float* __restrict__ kp, __bf16* __restrict__ kpbf) {
  const int bid = blockIdx.x;
  const int t = threadIdx.x;
  if (bid < 512) {
    wtq[(size_t)bid * 256 + t] =
        (t < 242) ? (__bf16)W_qp[(size_t)t * 512 + bid] : (__bf16)0.f;
  } else if (bid < 1024) {
    const int c = bid - 512;
    wkp_t[(size_t)c * 256 + t] =
        (t < 242) ? (__bf16)W_kp[(size_t)t * 512 + c] : (__bf16)0.f;
  } else {
    const int r = bid - 1024;
    kpbf[(size_t)r * 256 + t] =
        (t < 242) ? (__bf16)kp[(size_t)r * 242 + t] : (__bf16)0.f;
  }
}

// =====================================================================
// Generic transpose+convert (LDS-tiled): W [NK][NC] f32 -> Wt [NC][NK]
// =====================================================================
__device__ __forceinline__ void wtrans_body(const float* __restrict__ W,
                                            __bf16* __restrict__ Wt, int NC,
                                            int NK, int bx, int by) {
  __shared__ float T[32][33];
  const int t = threadIdx.x;
  const int c0 = bx * 32;
  const int k0 = by * 32;
#pragma unroll
  for (int r = 0; r < 4; ++r) {
    const int idx = r * 256 + t;
    const int i = idx >> 5, j = idx & 31;
    const int c = c0 + j;
    T[i][j] = (c < NC) ? W[(size_t)(k0 + i) * NC + c] : 0.f;
  }
  __syncthreads();
#pragma unroll
  for (int r = 0; r < 4; ++r) {
    const int idx = r * 256 + t;
    const int i = idx >> 5, j = idx & 31;
    const int c = c0 + i;
    if (c < NC) Wt[(size_t)c * NK + k0 + j] = (__bf16)T[j][i];
  }
}

__global__ __launch_bounds__(256) void wtrans_kernel(
    const float* __restrict__ W, __bf16* __restrict__ Wt, int NC, int NK) {
  wtrans_body(W, Wt, NC, NK, blockIdx.x, blockIdx.y);
}

__global__ __launch_bounds__(256) void wtrans4_kernel(
    const float* __restrict__ W0, const float* __restrict__ W1,
    const float* __restrict__ W2, const float* __restrict__ W3,
    __bf16* __restrict__ T0, __bf16* __restrict__ T1,
    __bf16* __restrict__ T2, __bf16* __restrict__ T3) {
  const float* W = (blockIdx.z == 0) ? W0 : (blockIdx.z == 1) ? W1
                   : (blockIdx.z == 2) ? W2 : W3;
  __bf16* Wt = (blockIdx.z == 0) ? T0 : (blockIdx.z == 1) ? T1
               : (blockIdx.z == 2) ? T2 : T3;
  wtrans_body(W, Wt, 512, 512, blockIdx.x, blockIdx.y);
}

// =====================================================================
// Register GEMM, K=512: one 16x16 tile per wave, no LDS, no barriers.
// =====================================================================
template <typename OutT>
__global__ __launch_bounds__(256) void reg_gemm512_kernel(
    const __bf16* __restrict__ A, int lda, const __bf16* __restrict__ Wt,
    const float* __restrict__ bias, OutT* __restrict__ C, int ldc) {
  const int t = threadIdx.x, lane = t & 63, w = t >> 6;
  const int n0 = blockIdx.x * 16;
  const int m0 = blockIdx.y * 64 + w * 16;
  const int fr = lane & 15, fq = lane >> 4;
  const __bf16* arow = A + (size_t)(m0 + fr) * lda + fq * 8;
  const __bf16* brow = Wt + (size_t)(n0 + fr) * 512 + fq * 8;
  f32x4 acc = f32x4{0.f, 0.f, 0.f, 0.f};
#pragma unroll
  for (int ks = 0; ks < 16; ++ks) {
    bf16x8 a = *reinterpret_cast<const bf16x8*>(arow + ks * 32);
    bf16x8 b = *reinterpret_cast<const bf16x8*>(brow + ks * 32);
    acc = mfma16(a, b, acc);
  }
  const int col = n0 + fr;
  const float bv = bias[col];
  const int r0 = m0 + fq * 4;
#pragma unroll
  for (int r = 0; r < 4; ++r)
    C[(size_t)(r0 + r) * ldc + col] = (OutT)(acc[r] + bv);
}

// K+V in one launch
__global__ __launch_bounds__(256) void kv_reg_gemm_kernel(
    const __bf16* __restrict__ A, const __bf16* __restrict__ wk_t,
    const float* __restrict__ bk, const __bf16* __restrict__ wv_t,
    const float* __restrict__ bv, __bf16* __restrict__ kout,
    __bf16* __restrict__ vout) {
  const __bf16* Wt = blockIdx.z ? wv_t : wk_t;
  const float* bias = blockIdx.z ? bv : bk;
  __bf16* C = blockIdx.z ? vout : kout;
  const int t = threadIdx.x, lane = t & 63, w = t >> 6;
  const int n0 = blockIdx.x * 16;
  const int m0 = blockIdx.y * 64 + w * 16;
  const int fr = lane & 15, fq = lane >> 4;
  const __bf16* arow = A + (size_t)(m0 + fr) * 512 + fq * 8;
  const __bf16* brow = Wt + (size_t)(n0 + fr) * 512 + fq * 8;
  f32x4 acc = f32x4{0.f, 0.f, 0.f, 0.f};
#pragma unroll
  for (int ks = 0; ks < 16; ++ks) {
    bf16x8 a = *reinterpret_cast<const bf16x8*>(arow + ks * 32);
    bf16x8 b = *reinterpret_cast<const bf16x8*>(brow + ks * 32);
    acc = mfma16(a, b, acc);
  }
  const int col = n0 + fr;
  const float bvv = bias[col];
  const int r0 = m0 + fq * 4;
#pragma unroll
  for (int r = 0; r < 4; ++r)
    C[(size_t)(r0 + r) * 512 + col] = (__bf16)(acc[r] + bvv);
}

// CTC head register GEMM (K=1024)
__global__ __launch_bounds__(256) void ctc_gemm_kernel(
    const __bf16* __restrict__ A, const __bf16* __restrict__ Wt,
    const float* __restrict__ bias, float* __restrict__ out) {
  const int t = threadIdx.x, lane = t & 63, w = t >> 6;
  const int n0 = blockIdx.x * 16;
  const int m0 = blockIdx.y * 64 + w * 16;
  const int fr = lane & 15, fq = lane >> 4;
  const __bf16* arow = A + (size_t)(m0 + fr) * 1024 + fq * 8;
  const __bf16* brow = Wt + (size_t)(n0 + fr) * 1024 + fq * 8;
  f32x4 acc = f32x4{0.f, 0.f, 0.f, 0.f};
#pragma unroll
  for (int ks = 0; ks < 32; ++ks) {
    bf16x8 a = *reinterpret_cast<const bf16x8*>(arow + ks * 32);
    bf16x8 b = *reinterpret_cast<const bf16x8*>(brow + ks * 32);
    acc = mfma16(a, b, acc);
  }
  const int col = n0 + fr;
  const float bv = bias[col];
  const int r0 = m0 + fq * 4;
#pragma unroll
  for (int r = 0; r < 4; ++r)
    out[(size_t)(r0 + r) * 1296 + col] = acc[r] + bv;
}

// =====================================================================
// Fused attention (unchanged, proven)
// =====================================================================
__global__ __launch_bounds__(256) void attn_fused_kernel(
    const __bf16* __restrict__ q, const __bf16* __restrict__ k,
    const __bf16* __restrict__ v, const int* __restrict__ lens,
    __bf16* __restrict__ ctx) {
  __shared__ __bf16 Qs[64 * 72];
  __shared__ __bf16 Ps[64 * 520];
  __shared__ __bf16 KVs[64 * 520];
  const int t = threadIdx.x, lane = t & 63, w = t >> 6;
  const int bh = blockIdx.x, b = bh >> 3, h = bh & 7;
  const int L = lens[b];
  const int sdiv = (L + 511) >> 9;
  const int new_len = (L + sdiv - 1) / sdiv;
  const size_t qbase = (size_t)b * 64 * 512 + h * 64;
  const size_t kbase = (size_t)b * 512 * 512 + h * 64;
  const size_t vbase = kbase;
  const int fr = lane & 15, fkq = (lane >> 4) * 8;

#pragma unroll
  for (int rep = 0; rep < 4; ++rep) {
    const int gidx = rep * 256 + t;
    const int row = gidx >> 4, c = (gidx & 15) * 4;
    *reinterpret_cast<bf16x4*>(&Qs[row * 72 + c]) =
        *reinterpret_cast<const bf16x4*>(&q[qbase + (size_t)row * 512 + c]);
  }
  f32x4 acc[32];
#pragma unroll
  for (int nt = 0; nt < 32; ++nt) acc[nt] = f32x4{0.f, 0.f, 0.f, 0.f};
  for (int ks = 0; ks < 2; ++ks) {
    const int k0 = ks * 32;
#pragma unroll
    for (int rep = 0; rep < 16; ++rep) {
      const int gidx = rep * 256 + t;
      const int row = gidx >> 3, c = (gidx & 7) * 4;
      *reinterpret_cast<bf16x4*>(&KVs[row * 40 + c]) =
          *reinterpret_cast<const bf16x4*>(&k[kbase + (size_t)row * 512 + k0 + c]);
    }
    __syncthreads();
    const bf16x8 af =
        *reinterpret_cast<const bf16x8*>(&Qs[(w * 16 + fr) * 72 + k0 + fkq]);
#pragma unroll
    for (int nt = 0; nt < 32; ++nt) {
      bf16x8 bf = *reinterpret_cast<const bf16x8*>(&KVs[(nt * 16 + fr) * 40 + fkq]);
      acc[nt] = mfma16(af, bf, acc[nt]);
    }
    __syncthreads();
  }
  const float scale = 0.125f;
#pragma unroll
  for (int r = 0; r < 4; ++r) {
    float mx = -3.0e38f;
#pragma unroll
    for (int nt = 0; nt < 32; ++nt) {
      const int col = nt * 16 + fr;
      const float sv = acc[nt][r] * scale;
      if (col < new_len) mx = fmaxf(mx, sv);
    }
#pragma unroll
    for (int off = 1; off < 16; off <<= 1) mx = fmaxf(mx, __shfl_xor(mx, off, 64));
    float sum = 0.f;
#pragma unroll
    for (int nt = 0; nt < 32; ++nt) {
      const int col = nt * 16 + fr;
      const float e = (col < new_len) ? __expf(acc[nt][r] * scale - mx) : 0.f;
      acc[nt][r] = e;
      sum += e;
    }
#pragma unroll
    for (int off = 1; off < 16; off <<= 1) sum += __shfl_xor(sum, off, 64);
    const float inv = 1.f / sum;
    const int row = w * 16 + ((lane >> 4) << 2) + r;
#pragma unroll
    for (int nt = 0; nt < 32; ++nt)
      Ps[row * 520 + nt * 16 + fr] = (__bf16)(acc[nt][r] * inv);
  }
  __syncthreads();
  {
    const int d = t & 63;
    const int kc = (t >> 6) * 128;
    const int sw = (d & 7) << 3;
#pragma unroll
    for (int j8 = 0; j8 < 16; ++j8) {
      const int kv0 = kc + j8 * 8;
      bf16x8 tmp;
#pragma unroll
      for (int jj = 0; jj < 8; ++jj)
        tmp[jj] = v[vbase + (size_t)(kv0 + jj) * 512 + d];
      *reinterpret_cast<bf16x8*>(&KVs[d * 520 + (kv0 ^ sw)]) = tmp;
    }
  }
  __syncthreads();
  f32x4 acc2[4];
#pragma unroll
  for (int nt = 0; nt < 4; ++nt) acc2[nt] = f32x4{0.f, 0.f, 0.f, 0.f};
  const int swr = (fr & 7) << 3;
#pragma unroll
  for (int s = 0; s < 16; ++s) {
    const int k0 = s * 32;
    const bf16x8 af =
        *reinterpret_cast<const bf16x8*>(&Ps[(w * 16 + fr) * 520 + k0 + fkq]);
#pragma unroll
    for (int nt = 0; nt < 4; ++nt) {
      bf16x8 bf = *reinterpret_cast<const bf16x8*>(
          &KVs[(nt * 16 + fr) * 520 + ((k0 + fkq) ^ swr)]);
      acc2[nt] = mfma16(af, bf, acc2[nt]);
    }
  }
  const int rq = (lane >> 4) * 4;
  const size_t cbase = (size_t)b * 64 * 512 + h * 64;
#pragma unroll
  for (int nt = 0; nt < 4; ++nt)
#pragma unroll
    for (int r = 0; r < 4; ++r)
      ctx[cbase + (size_t)(w * 16 + rq + r) * 512 + nt * 16 + fr] =
          (__bf16)acc2[nt][r];
}

// LayerNorm over rows of 512, bf16 output into fusedbf[:, 512:1024]
__global__ __launch_bounds__(256) void ln_bf16_kernel(
    const float* __restrict__ x, const float* __restrict__ g,
    const float* __restrict__ bt, __bf16* __restrict__ ybf) {
  __shared__ float red[8];
  const int t = threadIdx.x;
  const size_t off = (size_t)blockIdx.x * 512;
  const float a = x[off + t], b2 = x[off + t + 256];
  float s = a + b2, sq = a * a + b2 * b2;
  blockRed2(s, sq, red);
  const float m = s * (1.f / 512.f);
  const float var = sq * (1.f / 512.f) - m * m;
  const float rs = rsqrtf(var + 1e-5f);
  __bf16* yrow = ybf + (size_t)blockIdx.x * 1024;
  yrow[t] = (__bf16)((a - m) * rs * g[t] + bt[t]);
  yrow[t + 256] = (__bf16)((b2 - m) * rs * g[t + 256] + bt[t + 256]);
}

// =====================================================================
// Workspace layout (re-audited for phase-1 concurrency; ws >= 36 MB
// proven in rounds 1-6 where partials spanned ws+12..36):
//   ws+ 0.. 1    kptmp f32 (phase1 -> reduce_ln)
//   ws+ 1..1.5   qbuf bf16 (q -> attn)
//   ws+1.5..2    ctxbf bf16 (attn -> wo)
//   ws+ 2.. 3    wtq 256KB (prep3 -> phase1) / ctxo f32 (wo -> ln_bf16)
//   ws+ 3.. 4    fusedbf (reduce_ln -> q, ln_bf16 -> ctc)
//   ws+ 4.. 8    pooled bf16 (phase1 -> kv)  [EXCLUSIVE: pool runs
//                concurrently with img -> must not overlay partials]
//   ws+ 8..32.5  partials bf16 49x512KB (phase1 -> reduce_ln)
//     after death: kbuf 8..12, vbuf 12..16, wtc 16..18.6
//   ws+32.5..34.5 wq_t/wk_t/wv_t/wo_t
//   ws+34.5..34.75 kpbf; 34.75..35 wkp_t
// =====================================================================
extern "C" void kernel_launch(void* const* d_in, const int* in_sizes, int n_in,
                              void* d_out, int out_size, void* d_ws,
                              size_t ws_size, hipStream_t stream) {
  const float* images = (const float*)d_in[0];
  const float* qgrids = (const float*)d_in[1];
  const float* keypoints = (const float*)d_in[2];
  const int* qlens = (const int*)d_in[3];
  const float* W_img = (const float*)d_in[4];
  const float* b_img = (const float*)d_in[5];
  const float* W_kp = (const float*)d_in[6];
  const float* b_kp = (const float*)d_in[7];
  const float* g_kp = (const float*)d_in[8];
  const float* bt_kp = (const float*)d_in[9];
  const float* W_qp = (const float*)d_in[10];
  const float* b_qp = (const float*)d_in[11];
  const float* g_qln = (const float*)d_in[12];
  const float* bt_qln = (const float*)d_in[13];
  const float* Wq = (const float*)d_in[14];
  const float* bq = (const float*)d_in[15];
  const float* Wk = (const float*)d_in[16];
  const float* bk = (const float*)d_in[17];
  const float* Wv = (const float*)d_in[18];
  const float* bv = (const float*)d_in[19];
  const float* Wo = (const float*)d_in[20];
  const float* bo = (const float*)d_in[21];
  const float* g_attn = (const float*)d_in[22];
  const float* bt_attn = (const float*)d_in[23];
  const float* W_ctc = (const float*)d_in[24];
  const float* b_ctc = (const float*)d_in[25];
  float* out = (float*)d_out;

  const size_t MB = 1u << 20;
  const size_t KB = 1u << 10;
  if (ws_size < 35 * MB) return;
  char* ws = (char*)d_ws;
  float* kptmp = (float*)(ws);
  __bf16* qbuf = (__bf16*)(ws + 1 * MB);
  __bf16* ctxbf = (__bf16*)(ws + 1 * MB + 512 * KB);
  __bf16* wtq = (__bf16*)(ws + 2 * MB);
  float* ctxo = (float*)(ws + 2 * MB);
  __bf16* fusedbf = (__bf16*)(ws + 3 * MB);
  __bf16* pooled = (__bf16*)(ws + 4 * MB);
  __bf16* partials = (__bf16*)(ws + 8 * MB);
  __bf16* kbuf = (__bf16*)(ws + 8 * MB);    // after partials die
  __bf16* vbuf = (__bf16*)(ws + 12 * MB);   // after partials die
  __bf16* wtc = (__bf16*)(ws + 16 * MB);    // after partials die
  __bf16* wq_t = (__bf16*)(ws + 32 * MB + 512 * KB);
  __bf16* wk_t = (__bf16*)(ws + 33 * MB);
  __bf16* wv_t = (__bf16*)(ws + 33 * MB + 512 * KB);
  __bf16* wo_t = (__bf16*)(ws + 34 * MB);
  __bf16* kpbf = (__bf16*)(ws + 34 * MB + 512 * KB);
  __bf16* wkp_t = (__bf16*)(ws + 34 * MB + 768 * KB);

  // 1) prep: wqp^T + wkp^T + kp cast
  prep3_kernel<<<1536, 256, 0, stream>>>(W_qp, wtq, W_kp, wkp_t, keypoints,
                                         kpbf);
  // 2) qkvo weight transposes
  wtrans4_kernel<<<dim3(16, 16, 4), 256, 0, stream>>>(Wq, Wk, Wv, Wo, wq_t,
                                                      wk_t, wv_t, wo_t);
  // 3) phase-1 fused: pool(256) | img(784) | kp(128)
  phase1_kernel<<<1168, 512, 0, stream>>>(images, W_img, partials, qgrids,
                                          qlens, wtq, b_qp, g_qln, bt_qln,
                                          pooled, kpbf, wkp_t, b_kp, kptmp);
  // 4) reduce_ln: LN(kptmp) + b_img + sum(partials) -> fusedbf[:, :512]
  reduce_ln_kernel<<<512, 256, 0, stream>>>(kptmp, g_kp, bt_kp, partials,
                                            b_img, fusedbf);
  // 5) ctc weight transpose (partials dead -> wtc region free)
  wtrans_kernel<<<dim3(41, 32), 256, 0, stream>>>(W_ctc, wtc, 1296, 1024);
  // 6) k + v via register GEMM
  kv_reg_gemm_kernel<<<dim3(32, 64, 2), 256, 0, stream>>>(pooled, wk_t, bk,
                                                          wv_t, bv, kbuf, vbuf);
  // 7) q via register GEMM (A = fusedbf low-half, lda=1024)
  reg_gemm512_kernel<__bf16><<<dim3(32, 8), 256, 0, stream>>>(
      fusedbf, 1024, wq_t, bq, qbuf, 512);
  // 8) fused attention
  attn_fused_kernel<<<64, 256, 0, stream>>>(qbuf, kbuf, vbuf, qlens, ctxbf);
  // 9) ctx @ Wo + bo (f32), then LN -> fusedbf[:, 512:]
  reg_gemm512_kernel<float><<<dim3(32, 8), 256, 0, stream>>>(
      ctxbf, 512, wo_t, bo, ctxo, 512);
  ln_bf16_kernel<<<512, 256, 0, stream>>>(ctxo, g_attn, bt_attn, fusedbf + 512);
  // 10) out = fusedbf @ Wt_ctc^T + b_ctc
  ctc_gemm_kernel<<<dim3(81, 8), 256, 0, stream>>>(fusedbf, wtc, b_ctc, out);
}